// Round 8
// baseline (779.235 us; speedup 1.0000x reference)
//
#include <hip/hip_runtime.h>
#include <hip/hip_cooperative_groups.h>

namespace cg = cooperative_groups;

#define LOG_2PI_F 1.8378770664093453f

constexpr int BC = 1024, CC = 16, PV = 16, LV = 64, BB = 4;
constexpr int CH = (PV + 1) * BC;
constexpr int SLAB = BB * CC * LV;           // 4096
constexpr int SLABTOT = 2 * SLAB + BB * CC;  // 8256
constexpr int NSLAB_SM = 32;

typedef __attribute__((ext_vector_type(4))) short short4v;
typedef __attribute__((ext_vector_type(8))) short short8v;
typedef __attribute__((ext_vector_type(16))) float f32x16;
typedef __attribute__((ext_vector_type(4))) unsigned short us4;

union ABfrag { short8v v; short4v h[2]; unsigned short u[8]; };

__device__ __forceinline__ unsigned short f2bf(float f) {
  unsigned u = __float_as_uint(f);
  u += 0x7fffu + ((u >> 16) & 1u);  // RNE
  return (unsigned short)(u >> 16);
}

// ====================== fused cooperative kernel ======================
// NCAPB capsules per block, 512 threads (8 waves), wave w owns c=2w..2w+1.
// MFMA v_mfma_f32_32x32x16_bf16: A m=lane&31,k=8h+j ; B n=lane&31,k=8h+j ;
// C/D col=lane&31, row=(reg&3)+8*(reg>>2)+4*h   [m74/m101 verified]
template <int NCAPB, int MINW>
__global__ __launch_bounds__(512, MINW) void em_fused(
    const float* __restrict__ x, const float* __restrict__ W,
    const float* __restrict__ beta_v, const float* __restrict__ beta_a,
    const float* __restrict__ lam, float* __restrict__ Spart,
    float* __restrict__ Sred0, float* __restrict__ Sred1,
    float* __restrict__ out) {
  constexpr int NBLK = BC / NCAPB;
  cg::grid_group grid = cg::this_grid();
  const int bid = blockIdx.x, t = threadIdx.x;
  const int w = t >> 6, lane = t & 63;
  const int ln31 = lane & 31, h = lane >> 5;
  const int cbase = 2 * w;

  float* S1p = Spart + (size_t)bid * SLABTOT;
  float* S2p = S1p + SLAB;
  float* Srp = S1p + 2 * SLAB;

  __shared__ __align__(16) unsigned short pbf[NCAPB][64][20];
  __shared__ __align__(16) float act_s[NCAPB][64];
  __shared__ float T_s[64];
  __shared__ float sr_s[64];
  __shared__ float muS[4096];
  __shared__ float sc_s[NCAPB][64][17];
  __shared__ __align__(16) float rh2[NCAPB][16][64];
  __shared__ float lsum_s[64][8];

  // ---- W -> bf16 fragments in registers, once, for all NCAPB capsules ----
  short8v wf[NCAPB][4];
#pragma unroll
  for (int cap = 0; cap < NCAPB; ++cap) {
    const int i = bid + cap * NBLK;
#pragma unroll
    for (int cl_ = 0; cl_ < 2; ++cl_)
#pragma unroll
      for (int lh = 0; lh < 2; ++lh) {
        const float* src = W + ((size_t)(cbase + cl_) * BC + i) * 1024 +
                           (lh * 32 + ln31) * 16 + 8 * h;
        const float4 v0 = *reinterpret_cast<const float4*>(src);
        const float4 v1 = *reinterpret_cast<const float4*>(src + 4);
        ABfrag f;
        f.u[0] = f2bf(v0.x); f.u[1] = f2bf(v0.y);
        f.u[2] = f2bf(v0.z); f.u[3] = f2bf(v0.w);
        f.u[4] = f2bf(v1.x); f.u[5] = f2bf(v1.y);
        f.u[6] = f2bf(v1.z); f.u[7] = f2bf(v1.w);
        wf[cap][cl_ * 2 + lh] = f.v;
      }
  }
#pragma unroll
  for (int cap = 0; cap < NCAPB; ++cap)
#pragma unroll
    for (int k = 0; k < 4; ++k) asm volatile("" : "+v"(wf[cap][k]));  // pin

  // ---- stage pose -> bf16 LDS, act -> f32 ----
#pragma unroll
  for (int capq = 0; capq < NCAPB; capq += 2) {
    const int cap = capq + (t >> 8), tt = t & 255;
    const int b = tt >> 6, p = (tt >> 2) & 15, q = tt & 3;
    const int i = bid + cap * NBLK;
    const float4 v = *reinterpret_cast<const float4*>(
        x + ((size_t)(b * CH + p * BC + i)) * 16 + 4 * q);
    pbf[cap][b * 16 + 4 * q + 0][p] = f2bf(v.x);
    pbf[cap][b * 16 + 4 * q + 1][p] = f2bf(v.y);
    pbf[cap][b * 16 + 4 * q + 2][p] = f2bf(v.z);
    pbf[cap][b * 16 + 4 * q + 3][p] = f2bf(v.w);
  }
  if (t < 64 * NCAPB) {
    const int cap = t >> 6, r = t & 63;
    const int b = r >> 4, xy = r & 15;
    act_s[cap][r] = x[((size_t)(b * CH + PV * BC + bid + cap * NBLK)) * 16 + xy];
  }
  __syncthreads();

  const f32x16 zero16 = {};

  // ================= PASS 0: uniform R stats =================
#pragma unroll
  for (int pair = 0; pair < 2; ++pair) {
    float p1[4][2] = {}, p2[4][2] = {};
#pragma unroll
    for (int cap = 0; cap < NCAPB; ++cap) {
      ABfrag A;
      const int r = pair * 32 + ln31;
      A.h[0] = *reinterpret_cast<const short4v*>(&pbf[cap][r][8 * h]);
      A.h[1] = *reinterpret_cast<const short4v*>(&pbf[cap][r][8 * h + 4]);
      float rq[16];
#pragma unroll
      for (int g = 0; g < 4; ++g) {
        const float4 v = *reinterpret_cast<const float4*>(
            &act_s[cap][pair * 32 + 8 * g + 4 * h]);
        rq[4 * g + 0] = fmaxf(v.x * 0.0625f, 0.01f);
        rq[4 * g + 1] = fmaxf(v.y * 0.0625f, 0.01f);
        rq[4 * g + 2] = fmaxf(v.z * 0.0625f, 0.01f);
        rq[4 * g + 3] = fmaxf(v.w * 0.0625f, 0.01f);
      }
#pragma unroll
      for (int cl_ = 0; cl_ < 2; ++cl_)
#pragma unroll
        for (int lh = 0; lh < 2; ++lh) {
          const f32x16 acc = __builtin_amdgcn_mfma_f32_32x32x16_bf16(
              A.v, wf[cap][cl_ * 2 + lh], zero16, 0, 0, 0);
          const int t4 = cl_ * 2 + lh;
#pragma unroll
          for (int j = 0; j < 16; ++j) {
            const float v = acc[j];
            const float rv = rq[j] * v;
            p1[t4][j >> 3] += rv;
            p2[t4][j >> 3] = fmaf(rv, v, p2[t4][j >> 3]);
          }
        }
    }
#pragma unroll
    for (int t4 = 0; t4 < 4; ++t4)
#pragma unroll
      for (int bh = 0; bh < 2; ++bh) {
        float v1 = p1[t4][bh]; v1 += __shfl_xor(v1, 32, 64);
        float v2 = p2[t4][bh]; v2 += __shfl_xor(v2, 32, 64);
        const int b = pair * 2 + bh, c = cbase + (t4 >> 1);
        const int idx = (b * CC + c) * LV + (t4 & 1) * 32 + ln31;
        if (h == 0) { S1p[idx] = v1; S2p[idx] = v2; }
      }
  }
  if (t < 64) {
    const int b = t >> 4;
    float s = 0.f;
#pragma unroll
    for (int cap = 0; cap < NCAPB; ++cap)
#pragma unroll
      for (int xy = 0; xy < 16; ++xy)
        s += fmaxf(act_s[cap][b * 16 + xy] * 0.0625f, 0.01f);
    Srp[t] = s;
  }
  __threadfence();
  grid.sync();  // ---- sync 1: partials visible ----

  // ---- reduce0 ----
  constexpr int NSC = NBLK / 32;
  if (bid < NSC * 17) {
    const int sc = bid / 17, ec = bid % 17;
    const int e = ec * 512 + t;
    if (e < SLABTOT) {
      float a = 0.f;
      const float* base = Spart + (size_t)(sc * 32) * SLABTOT + e;
#pragma unroll 8
      for (int s = 0; s < 32; ++s) a += base[(size_t)s * SLABTOT];
      atomicAdd(&Sred0[e], a);
    }
  }
  __threadfence();
  grid.sync();  // ---- sync 2: Sred0 complete ----

  // ---- stats0: EVERY block computes mu -> muS, T -> T_s (redundant) ----
  {
    const int bc = t >> 3, part = t & 7;
    const float inv = 1.f / Sred0[2 * SLAB + bc];
    float lsl = 0.f;
#pragma unroll
    for (int q = 0; q < 8; ++q) {
      const int idx = bc * 64 + part * 8 + q;
      const float m = Sred0[idx] * inv;
      const float s2 = fmaxf(Sred0[SLAB + idx] * inv - m * m, 0.01f);
      lsl += logf(s2);
      muS[idx] = m;
    }
    lsum_s[bc][part] = lsl;
  }
  __syncthreads();
  if (t < 64) {
    float lsum = 0.f;
#pragma unroll
    for (int q = 0; q < 8; ++q) lsum += lsum_s[t][q];
    const float sr = Sred0[2 * SLAB + t];
    const float z = lam[0] * (beta_a[t & 15] - (64.f * beta_v[0] + lsum) * sr);
    const float ac = 1.f / (1.f + expf(-z));
    T_s[t] = logf(ac) - 0.5f * (64.f * LOG_2PI_F + lsum);
    sr_s[t] = 0.f;
  }
  __syncthreads();

  // ================= PASS 1 phase A: scores =================
#pragma unroll
  for (int cap = 0; cap < NCAPB; ++cap)
#pragma unroll
    for (int pair = 0; pair < 2; ++pair) {
      ABfrag A;
      const int r = pair * 32 + ln31;
      A.h[0] = *reinterpret_cast<const short4v*>(&pbf[cap][r][8 * h]);
      A.h[1] = *reinterpret_cast<const short4v*>(&pbf[cap][r][8 * h + 4]);
#pragma unroll
      for (int cl_ = 0; cl_ < 2; ++cl_) {
        float scv[16];
#pragma unroll
        for (int j = 0; j < 16; ++j) scv[j] = 0.f;
#pragma unroll
        for (int lh = 0; lh < 2; ++lh) {
          const f32x16 acc = __builtin_amdgcn_mfma_f32_32x32x16_bf16(
              A.v, wf[cap][cl_ * 2 + lh], zero16, 0, 0, 0);
          const float mu0 =
              muS[((pair * 2 + 0) * CC + cbase + cl_) * LV + lh * 32 + ln31];
          const float mu1 =
              muS[((pair * 2 + 1) * CC + cbase + cl_) * LV + lh * 32 + ln31];
#pragma unroll
          for (int j = 0; j < 16; ++j) {
            const float d = acc[j] - ((j >> 3) ? mu1 : mu0);
            scv[j] = fmaf(d, d, scv[j]);
          }
        }
#pragma unroll
        for (int j = 0; j < 16; ++j) {
          float v = scv[j];
          v += __shfl_xor(v, 1, 64);  v += __shfl_xor(v, 2, 64);
          v += __shfl_xor(v, 4, 64);  v += __shfl_xor(v, 8, 64);
          v += __shfl_xor(v, 16, 64);
          if (ln31 == 0)
            sc_s[cap][pair * 32 + (j & 3) + 8 * (j >> 2) + 4 * h][cbase + cl_] = v;
        }
      }
    }
  __syncthreads();

  // ---- softmax over c ----
#pragma unroll
  for (int cap = 0; cap < NCAPB; ++cap) {
    const int r = t & 63, cq = t >> 6, b = r >> 4;
    float s[16];
#pragma unroll
    for (int cc = 0; cc < 16; ++cc) s[cc] = T_s[b * CC + cc] - sc_s[cap][r][cc];
    float m = s[0];
#pragma unroll
    for (int cc = 1; cc < 16; ++cc) m = fmaxf(m, s[cc]);
    float den = 0.f;
#pragma unroll
    for (int cc = 0; cc < 16; ++cc) { s[cc] = __expf(s[cc] - m); den += s[cc]; }
    const float a = act_s[cap][r] / den;
#pragma unroll
    for (int k = 0; k < 2; ++k) {
      const int cc = 2 * cq + k;
      const float rh = fmaxf(s[cc] * a, 0.01f);
      rh2[cap][cc][r] = rh;
      atomicAdd(&sr_s[b * CC + cc], rh);
    }
  }
  __syncthreads();

  // ================= PASS 1 phase B: final stats =================
#pragma unroll
  for (int pair = 0; pair < 2; ++pair) {
    float p1[4][2] = {}, p2[4][2] = {};
#pragma unroll
    for (int cap = 0; cap < NCAPB; ++cap) {
      ABfrag A;
      const int r = pair * 32 + ln31;
      A.h[0] = *reinterpret_cast<const short4v*>(&pbf[cap][r][8 * h]);
      A.h[1] = *reinterpret_cast<const short4v*>(&pbf[cap][r][8 * h + 4]);
#pragma unroll
      for (int cl_ = 0; cl_ < 2; ++cl_) {
        float rq[16];
#pragma unroll
        for (int g = 0; g < 4; ++g) {
          const float4 v = *reinterpret_cast<const float4*>(
              &rh2[cap][cbase + cl_][pair * 32 + 8 * g + 4 * h]);
          rq[4 * g + 0] = v.x; rq[4 * g + 1] = v.y;
          rq[4 * g + 2] = v.z; rq[4 * g + 3] = v.w;
        }
#pragma unroll
        for (int lh = 0; lh < 2; ++lh) {
          const f32x16 acc = __builtin_amdgcn_mfma_f32_32x32x16_bf16(
              A.v, wf[cap][cl_ * 2 + lh], zero16, 0, 0, 0);
          const int t4 = cl_ * 2 + lh;
#pragma unroll
          for (int j = 0; j < 16; ++j) {
            const float v = acc[j];
            const float rv = rq[j] * v;
            p1[t4][j >> 3] += rv;
            p2[t4][j >> 3] = fmaf(rv, v, p2[t4][j >> 3]);
          }
        }
      }
    }
#pragma unroll
    for (int t4 = 0; t4 < 4; ++t4)
#pragma unroll
      for (int bh = 0; bh < 2; ++bh) {
        float v1 = p1[t4][bh]; v1 += __shfl_xor(v1, 32, 64);
        float v2 = p2[t4][bh]; v2 += __shfl_xor(v2, 32, 64);
        const int b = pair * 2 + bh, c = cbase + (t4 >> 1);
        const int idx = (b * CC + c) * LV + (t4 & 1) * 32 + ln31;
        if (h == 0) { S1p[idx] = v1; S2p[idx] = v2; }
      }
  }
  if (t < 64) Srp[t] = sr_s[t];
  __threadfence();
  grid.sync();  // ---- sync 3 ----

  // ---- reduce1 ----
  if (bid < NSC * 17) {
    const int sc = bid / 17, ec = bid % 17;
    const int e = ec * 512 + t;
    if (e < SLABTOT) {
      float a = 0.f;
      const float* base = Spart + (size_t)(sc * 32) * SLABTOT + e;
#pragma unroll 8
      for (int s = 0; s < 32; ++s) a += base[(size_t)s * SLABTOT];
      atomicAdd(&Sred1[e], a);
    }
  }
  __threadfence();
  grid.sync();  // ---- sync 4 ----

  // ---- final stats + output (block 0 only) ----
  if (bid == 0) {
    const int bc = t >> 3, part = t & 7;
    const float inv = 1.f / Sred1[2 * SLAB + bc];
    float lsl = 0.f;
#pragma unroll
    for (int q = 0; q < 8; ++q) {
      const int l = part * 8 + q;
      const int idx = bc * 64 + l;
      const float m = Sred1[idx] * inv;
      const float s2 = fmaxf(Sred1[SLAB + idx] * inv - m * m, 0.01f);
      lsl += logf(s2);
      out[(size_t)(bc >> 4) * 1040 + (bc & 15) * 64 + l] = m;
    }
    lsum_s[bc][part] = lsl;
    __syncthreads();
    if (t < 64) {
      float lsum = 0.f;
#pragma unroll
      for (int q = 0; q < 8; ++q) lsum += lsum_s[t][q];
      const float sr = Sred1[2 * SLAB + t];
      const float z = lam[0] * (beta_a[t & 15] - (64.f * beta_v[0] + lsum) * sr);
      out[(size_t)(t >> 4) * 1040 + 1024 + (t & 15)] = 1.f / (1.f + expf(-z));
    }
  }
}

// ====================== round-6 fallback kernels ======================
template <int PASS, int STORE>
__global__ __launch_bounds__(512, 4) void em_sweep(
    const float* __restrict__ x, const float* __restrict__ W,
    const float* __restrict__ mu, const float* __restrict__ T,
    float* __restrict__ Spart, int nslab) {
  const int i = blockIdx.x, t = threadIdx.x;
  const int w = t >> 6, lane = t & 63;
  const int ln31 = lane & 31, h = lane >> 5;
  const int cbase = 2 * w;

  float* S1p = Spart + (size_t)(blockIdx.x % nslab) * SLABTOT;
  float* S2p = S1p + SLAB;
  float* Srp = S1p + 2 * SLAB;

  __shared__ __align__(16) unsigned short pbf[64][20];
  __shared__ float act_s[64];
  __shared__ float T_s[64];
  __shared__ float sr_s[64];
  __shared__ float sc_s[64][17];
  __shared__ float rh2[16][64];

  short8v wf[4];
#pragma unroll
  for (int cl_ = 0; cl_ < 2; ++cl_)
#pragma unroll
    for (int lh = 0; lh < 2; ++lh) {
      const float* src = W + ((size_t)(cbase + cl_) * BC + i) * 1024 +
                         (lh * 32 + ln31) * 16 + 8 * h;
      const float4 v0 = *reinterpret_cast<const float4*>(src);
      const float4 v1 = *reinterpret_cast<const float4*>(src + 4);
      ABfrag f;
      f.u[0] = f2bf(v0.x); f.u[1] = f2bf(v0.y);
      f.u[2] = f2bf(v0.z); f.u[3] = f2bf(v0.w);
      f.u[4] = f2bf(v1.x); f.u[5] = f2bf(v1.y);
      f.u[6] = f2bf(v1.z); f.u[7] = f2bf(v1.w);
      wf[cl_ * 2 + lh] = f.v;
    }
#pragma unroll
  for (int k = 0; k < 4; ++k) asm volatile("" : "+v"(wf[k]));

  if (t < 256) {
    const int b = t >> 6, p = (t >> 2) & 15, q = t & 3;
    const float4 v = *reinterpret_cast<const float4*>(
        x + ((size_t)(b * CH + p * BC + i)) * 16 + 4 * q);
    pbf[b * 16 + 4 * q + 0][p] = f2bf(v.x);
    pbf[b * 16 + 4 * q + 1][p] = f2bf(v.y);
    pbf[b * 16 + 4 * q + 2][p] = f2bf(v.z);
    pbf[b * 16 + 4 * q + 3][p] = f2bf(v.w);
  }
  if (t < 64) {
    const int b = t >> 4, xy = t & 15;
    act_s[t] = x[((size_t)(b * CH + PV * BC + i)) * 16 + xy];
    if (PASS == 1) { T_s[t] = T[t]; sr_s[t] = 0.f; }
  }

  float mur[2][2][4];
  if (PASS == 1) {
#pragma unroll
    for (int cl_ = 0; cl_ < 2; ++cl_)
#pragma unroll
      for (int lh = 0; lh < 2; ++lh)
#pragma unroll
        for (int b = 0; b < 4; ++b)
          mur[cl_][lh][b] = mu[(b * CC + cbase + cl_) * LV + lh * 32 + ln31];
  }
  __syncthreads();

  const f32x16 zero16 = {};

  if (PASS == 1) {
#pragma unroll
    for (int pair = 0; pair < 2; ++pair) {
      ABfrag A;
      {
        const int r = pair * 32 + ln31;
        A.h[0] = *reinterpret_cast<const short4v*>(&pbf[r][8 * h]);
        A.h[1] = *reinterpret_cast<const short4v*>(&pbf[r][8 * h + 4]);
      }
#pragma unroll
      for (int cl_ = 0; cl_ < 2; ++cl_) {
        float scv[16];
#pragma unroll
        for (int j = 0; j < 16; ++j) scv[j] = 0.f;
#pragma unroll
        for (int lh = 0; lh < 2; ++lh) {
          const f32x16 acc = __builtin_amdgcn_mfma_f32_32x32x16_bf16(
              A.v, wf[cl_ * 2 + lh], zero16, 0, 0, 0);
#pragma unroll
          for (int j = 0; j < 16; ++j) {
            const float d = acc[j] - mur[cl_][lh][pair * 2 + (j >> 3)];
            scv[j] = fmaf(d, d, scv[j]);
          }
        }
#pragma unroll
        for (int j = 0; j < 16; ++j) {
          float v = scv[j];
          v += __shfl_xor(v, 1, 64);  v += __shfl_xor(v, 2, 64);
          v += __shfl_xor(v, 4, 64);  v += __shfl_xor(v, 8, 64);
          v += __shfl_xor(v, 16, 64);
          if (ln31 == 0)
            sc_s[pair * 32 + (j & 3) + 8 * (j >> 2) + 4 * h][cbase + cl_] = v;
        }
      }
    }
    __syncthreads();
    {
      const int r = t & 63, cq = t >> 6, b = r >> 4;
      float s[16];
#pragma unroll
      for (int cc = 0; cc < 16; ++cc) s[cc] = T_s[b * CC + cc] - sc_s[r][cc];
      float m = s[0];
#pragma unroll
      for (int cc = 1; cc < 16; ++cc) m = fmaxf(m, s[cc]);
      float den = 0.f;
#pragma unroll
      for (int cc = 0; cc < 16; ++cc) { s[cc] = __expf(s[cc] - m); den += s[cc]; }
      const float a = act_s[r] / den;
#pragma unroll
      for (int k = 0; k < 2; ++k) {
        const int cc = 2 * cq + k;
        const float rh = fmaxf(s[cc] * a, 0.01f);
        rh2[cc][r] = rh;
        atomicAdd(&sr_s[b * CC + cc], rh);
      }
    }
    __syncthreads();
  }

#pragma unroll
  for (int pair = 0; pair < 2; ++pair) {
    ABfrag A;
    {
      const int r = pair * 32 + ln31;
      A.h[0] = *reinterpret_cast<const short4v*>(&pbf[r][8 * h]);
      A.h[1] = *reinterpret_cast<const short4v*>(&pbf[r][8 * h + 4]);
    }
    float p1[4][2] = {}, p2[4][2] = {};
#pragma unroll
    for (int cl_ = 0; cl_ < 2; ++cl_) {
      float rq[16];
      if (PASS == 1) {
#pragma unroll
        for (int g = 0; g < 4; ++g) {
          const float4 v = *reinterpret_cast<const float4*>(
              &rh2[cbase + cl_][pair * 32 + 8 * g + 4 * h]);
          rq[4 * g + 0] = v.x; rq[4 * g + 1] = v.y;
          rq[4 * g + 2] = v.z; rq[4 * g + 3] = v.w;
        }
      } else {
#pragma unroll
        for (int g = 0; g < 4; ++g) {
          const float4 v = *reinterpret_cast<const float4*>(
              &act_s[pair * 32 + 8 * g + 4 * h]);
          rq[4 * g + 0] = fmaxf(v.x * 0.0625f, 0.01f);
          rq[4 * g + 1] = fmaxf(v.y * 0.0625f, 0.01f);
          rq[4 * g + 2] = fmaxf(v.z * 0.0625f, 0.01f);
          rq[4 * g + 3] = fmaxf(v.w * 0.0625f, 0.01f);
        }
      }
#pragma unroll
      for (int lh = 0; lh < 2; ++lh) {
        const f32x16 acc = __builtin_amdgcn_mfma_f32_32x32x16_bf16(
            A.v, wf[cl_ * 2 + lh], zero16, 0, 0, 0);
        const int t4 = cl_ * 2 + lh;
#pragma unroll
        for (int j = 0; j < 16; ++j) {
          const float v = acc[j];
          const float rv = rq[j] * v;
          p1[t4][j >> 3] += rv;
          p2[t4][j >> 3] = fmaf(rv, v, p2[t4][j >> 3]);
        }
      }
    }
#pragma unroll
    for (int t4 = 0; t4 < 4; ++t4)
#pragma unroll
      for (int bh = 0; bh < 2; ++bh) {
        float v1 = p1[t4][bh]; v1 += __shfl_xor(v1, 32, 64);
        float v2 = p2[t4][bh]; v2 += __shfl_xor(v2, 32, 64);
        const int b = pair * 2 + bh, c = cbase + (t4 >> 1);
        const int idx = (b * CC + c) * LV + (t4 & 1) * 32 + ln31;
        if (STORE) {
          if (h == 0) { S1p[idx] = v1; S2p[idx] = v2; }
        } else if (h == 0) {
          atomicAdd(&S1p[idx], v1); atomicAdd(&S2p[idx], v2);
        }
      }
  }

  if (PASS == 1) {
    if (t < 64) { if (STORE) Srp[t] = sr_s[t]; else atomicAdd(&Srp[t], sr_s[t]); }
  } else {
    if (t < 64) {
      const int b = t >> 4;
      float s = 0.f;
#pragma unroll
      for (int xy = 0; xy < 16; ++xy) s += fmaxf(act_s[b * 16 + xy] * 0.0625f, 0.01f);
      if (STORE) Srp[t] = s; else atomicAdd(&Srp[t], s);
    }
  }
}

__global__ void reduce_slabs(const float* __restrict__ Spart, float* __restrict__ Sred,
                             int nslab, int chunk) {
  const int idx = blockIdx.x * 256 + threadIdx.x;
  if (idx >= SLABTOT) return;
  const int s0 = blockIdx.y * chunk;
  const int s1 = min(s0 + chunk, nslab);
  float a = 0.f;
#pragma unroll 8
  for (int s = s0; s < s1; s++) a += Spart[(size_t)s * SLABTOT + idx];
  atomicAdd(&Sred[idx], a);
}

template <int FINAL>
__global__ void stats_post(const float* __restrict__ Sred,
                           const float* __restrict__ beta_v,
                           const float* __restrict__ beta_a,
                           const float* __restrict__ lam,
                           float* __restrict__ mu_out, float* __restrict__ T_out,
                           float* __restrict__ out) {
  const int t = threadIdx.x;
  if (t >= 64) return;
  const int b = t >> 4, c = t & 15;
  const float* S1 = Sred;
  const float* S2 = Sred + SLAB;
  const float sr = Sred[2 * SLAB + b * CC + c];
  const float inv = 1.f / sr;
  const float bv = beta_v[0];
  float csum = 0.f, lsum = 0.f;
  for (int l = 0; l < LV; l++) {
    const int idx = (b * CC + c) * LV + l;
    const float m = S1[idx] * inv;
    float s2 = S2[idx] * inv - m * m;
    s2 = fmaxf(s2, 0.01f);
    const float ls = logf(s2);
    csum += bv + ls;
    lsum += ls;
    if (FINAL) out[(size_t)b * 1040 + c * LV + l] = m;
    else mu_out[idx] = m;
  }
  const float z = lam[0] * (beta_a[c] - csum * sr);
  const float ac = 1.f / (1.f + expf(-z));
  if (FINAL) out[(size_t)b * 1040 + 1024 + c] = ac;
  else T_out[b * CC + c] = logf(ac) - 0.5f * (64.f * LOG_2PI_F + lsum);
}

extern "C" void kernel_launch(void* const* d_in, const int* in_sizes, int n_in,
                              void* d_out, int out_size, void* d_ws, size_t ws_size,
                              hipStream_t stream) {
  const float* x = (const float*)d_in[0];
  const float* W = (const float*)d_in[1];
  const float* beta_v = (const float*)d_in[2];
  const float* beta_a = (const float*)d_in[3];
  const float* lam = (const float*)d_in[4];
  float* out = (float*)d_out;

  float* Spart = (float*)d_ws;
  float* Sred0 = Spart + (size_t)512 * SLABTOT;
  float* Sred1 = Sred0 + SLABTOT;

  // ---- tier 1 & 2: fused cooperative kernel ----
  hipMemsetAsync(Sred0, 0, 2 * SLABTOT * sizeof(float), stream);
  void* args[] = {(void*)&x,      (void*)&W,     (void*)&beta_v,
                  (void*)&beta_a, (void*)&lam,   (void*)&Spart,
                  (void*)&Sred0,  (void*)&Sred1, (void*)&out};
  hipError_t e = hipLaunchCooperativeKernel((void*)em_fused<2, 4>, dim3(512),
                                            dim3(512), args, 0, stream);
  if (e != hipSuccess) {
    (void)hipGetLastError();
    e = hipLaunchCooperativeKernel((void*)em_fused<4, 2>, dim3(256), dim3(512),
                                   args, 0, stream);
  }
  if (e == hipSuccess) return;
  (void)hipGetLastError();

  // ---- tier 3: proven multi-kernel path (round 6) ----
  const size_t need = ((size_t)BC * SLABTOT + SLABTOT + SLAB + 64) * sizeof(float);
  const int nslab = (ws_size >= need) ? BC : NSLAB_SM;
  const bool store = (nslab == BC);

  float* SpartF = (float*)d_ws;
  float* SredF = SpartF + (size_t)nslab * SLABTOT;
  float* muW = SredF + SLABTOT;
  float* Tw = muW + SLAB;

  const int chunk = 32;
  const dim3 rgrid((SLABTOT + 255) / 256, (nslab + chunk - 1) / chunk);

  if (!store) hipMemsetAsync(SpartF, 0, (size_t)nslab * SLABTOT * sizeof(float), stream);
  hipMemsetAsync(SredF, 0, SLABTOT * sizeof(float), stream);
  if (store) em_sweep<0, 1><<<dim3(BC), dim3(512), 0, stream>>>(x, W, nullptr, nullptr, SpartF, nslab);
  else       em_sweep<0, 0><<<dim3(BC), dim3(512), 0, stream>>>(x, W, nullptr, nullptr, SpartF, nslab);
  reduce_slabs<<<rgrid, dim3(256), 0, stream>>>(SpartF, SredF, nslab, chunk);
  stats_post<0><<<dim3(1), dim3(64), 0, stream>>>(SredF, beta_v, beta_a, lam, muW, Tw, nullptr);

  if (!store) hipMemsetAsync(SpartF, 0, (size_t)nslab * SLABTOT * sizeof(float), stream);
  hipMemsetAsync(SredF, 0, SLABTOT * sizeof(float), stream);
  if (store) em_sweep<1, 1><<<dim3(BC), dim3(512), 0, stream>>>(x, W, muW, Tw, SpartF, nslab);
  else       em_sweep<1, 0><<<dim3(BC), dim3(512), 0, stream>>>(x, W, muW, Tw, SpartF, nslab);
  reduce_slabs<<<rgrid, dim3(256), 0, stream>>>(SpartF, SredF, nslab, chunk);
  stats_post<1><<<dim3(1), dim3(64), 0, stream>>>(SredF, beta_v, beta_a, lam, nullptr, nullptr, out);
}

// Round 9
// 154.219 us; speedup vs baseline: 5.0528x; 5.0528x over previous
//
#include <hip/hip_runtime.h>

#define LOG_2PI_F 1.8378770664093453f

constexpr int BC = 1024, CC = 16, PV = 16, LV = 64, BB = 4;
constexpr int CH = (PV + 1) * BC;
constexpr int SLAB = BB * CC * LV;           // 4096
constexpr int SLABTOT = 2 * SLAB + BB * CC;  // 8256
constexpr int NSLAB_SM = 32;

typedef __attribute__((ext_vector_type(4))) short short4v;
typedef __attribute__((ext_vector_type(8))) short short8v;
typedef __attribute__((ext_vector_type(16))) float f32x16;

union ABfrag { short8v v; short4v h[2]; unsigned short u[8]; };

__device__ __forceinline__ unsigned short f2bf(float f) {
  unsigned u = __float_as_uint(f);
  u += 0x7fffu + ((u >> 16) & 1u);  // RNE
  return (unsigned short)(u >> 16);
}

__device__ __forceinline__ short8v cvt8(const float4 a, const float4 b) {
  ABfrag f;
  f.u[0] = f2bf(a.x); f.u[1] = f2bf(a.y); f.u[2] = f2bf(a.z); f.u[3] = f2bf(a.w);
  f.u[4] = f2bf(b.x); f.u[5] = f2bf(b.y); f.u[6] = f2bf(b.z); f.u[7] = f2bf(b.w);
  return f.v;
}

// 512 blocks x 512 threads; block pipelines TWO capsules: i0=bid, i1=bid+512.
// 8 waves; wave w owns c = 2w..2w+1.
// MFMA v_mfma_f32_32x32x16_bf16: A m=lane&31,k=8h+j ; B n=lane&31,k=8h+j ;
// C/D col=lane&31, row=(reg&3)+8*(reg>>2)+4*h   [m74/m101 verified]
// cap1's W loads are ISSUED before cap0's compute (raw fp32 in 32 VGPRs) and
// converted at the cap boundary -> HBM latency hides under cap0 compute.
template <int PASS, int STORE>
__global__ __launch_bounds__(512, 4) void em_sweep2(
    const float* __restrict__ x, const float* __restrict__ W,
    const float* __restrict__ mu, const float* __restrict__ T,
    float* __restrict__ Spart, int nslab) {
  const int bid = blockIdx.x, t = threadIdx.x;
  const int w = t >> 6, lane = t & 63;
  const int ln31 = lane & 31, h = lane >> 5;
  const int cbase = 2 * w;

  __shared__ __align__(16) unsigned short pbf[2][64][20];  // pitch 40B
  __shared__ float act_s[2][64];
  __shared__ float T_s[64];
  __shared__ float sr_s[2][64];
  __shared__ float sc_s[64][17];
  __shared__ float rh2[16][64];

  // ---- prologue: issue cap0 W loads ----
  float4 wraw[8];
#pragma unroll
  for (int k = 0; k < 4; ++k) {
    const int cl_ = k >> 1, lh = k & 1;
    const float* src = W + ((size_t)(cbase + cl_) * BC + bid) * 1024 +
                       (lh * 32 + ln31) * 16 + 8 * h;
    wraw[2 * k] = *reinterpret_cast<const float4*>(src);
    wraw[2 * k + 1] = *reinterpret_cast<const float4*>(src + 4);
  }

  // ---- stage pose (both caps) -> bf16 LDS; act; T; sr zero ----
  {
    const int cap = t >> 8, tt = t & 255;
    const int b = tt >> 6, p = (tt >> 2) & 15, q = tt & 3;
    const int i = bid + cap * 512;
    const float4 v = *reinterpret_cast<const float4*>(
        x + ((size_t)(b * CH + p * BC + i)) * 16 + 4 * q);
    pbf[cap][b * 16 + 4 * q + 0][p] = f2bf(v.x);
    pbf[cap][b * 16 + 4 * q + 1][p] = f2bf(v.y);
    pbf[cap][b * 16 + 4 * q + 2][p] = f2bf(v.z);
    pbf[cap][b * 16 + 4 * q + 3][p] = f2bf(v.w);
  }
  if (t < 128) {
    const int cap = t >> 6, r = t & 63;
    const int b = r >> 4, xy = r & 15;
    act_s[cap][r] = x[((size_t)(b * CH + PV * BC + bid + cap * 512)) * 16 + xy];
    if (PASS == 1) sr_s[cap][r] = 0.f;
  }
  if (PASS == 1 && t < 64) T_s[t] = T[t];

  float mur[2][2][4];  // [c_local][lh][b]; same for both caps (mu has no i dep)
  if (PASS == 1) {
#pragma unroll
    for (int cl_ = 0; cl_ < 2; ++cl_)
#pragma unroll
      for (int lh = 0; lh < 2; ++lh)
#pragma unroll
        for (int b = 0; b < 4; ++b)
          mur[cl_][lh][b] = mu[(b * CC + cbase + cl_) * LV + lh * 32 + ln31];
  }

  // convert cap0 W -> bf16 frags, pin against rematerialization
  short8v wf[4];
#pragma unroll
  for (int k = 0; k < 4; ++k) wf[k] = cvt8(wraw[2 * k], wraw[2 * k + 1]);
#pragma unroll
  for (int k = 0; k < 4; ++k) asm volatile("" : "+v"(wf[k]));
  __syncthreads();

  const f32x16 zero16 = {};

#pragma unroll
  for (int cap = 0; cap < 2; ++cap) {
    // ---- prefetch cap1 W while computing cap0 ----
    if (cap == 0) {
#pragma unroll
      for (int k = 0; k < 4; ++k) {
        const int cl_ = k >> 1, lh = k & 1;
        const float* src = W + ((size_t)(cbase + cl_) * BC + bid + 512) * 1024 +
                           (lh * 32 + ln31) * 16 + 8 * h;
        wraw[2 * k] = *reinterpret_cast<const float4*>(src);
        wraw[2 * k + 1] = *reinterpret_cast<const float4*>(src + 4);
      }
    }

    float* S1p = Spart + (size_t)((bid + cap * 512) % nslab) * SLABTOT;
    float* S2p = S1p + SLAB;
    float* Srp = S1p + 2 * SLAB;

    if (PASS == 1) {
      // ---- phase A: scores ----
#pragma unroll
      for (int pair = 0; pair < 2; ++pair) {
        ABfrag A;
        const int r = pair * 32 + ln31;
        A.h[0] = *reinterpret_cast<const short4v*>(&pbf[cap][r][8 * h]);
        A.h[1] = *reinterpret_cast<const short4v*>(&pbf[cap][r][8 * h + 4]);
#pragma unroll
        for (int cl_ = 0; cl_ < 2; ++cl_) {
          float scv[16];
#pragma unroll
          for (int j = 0; j < 16; ++j) scv[j] = 0.f;
#pragma unroll
          for (int lh = 0; lh < 2; ++lh) {
            const f32x16 acc = __builtin_amdgcn_mfma_f32_32x32x16_bf16(
                A.v, wf[cl_ * 2 + lh], zero16, 0, 0, 0);
#pragma unroll
            for (int j = 0; j < 16; ++j) {
              const float d = acc[j] - mur[cl_][lh][pair * 2 + (j >> 3)];
              scv[j] = fmaf(d, d, scv[j]);
            }
          }
#pragma unroll
          for (int j = 0; j < 16; ++j) {  // sum over 32 cols
            float v = scv[j];
            v += __shfl_xor(v, 1, 64);  v += __shfl_xor(v, 2, 64);
            v += __shfl_xor(v, 4, 64);  v += __shfl_xor(v, 8, 64);
            v += __shfl_xor(v, 16, 64);
            if (ln31 == 0)
              sc_s[pair * 32 + (j & 3) + 8 * (j >> 2) + 4 * h][cbase + cl_] = v;
          }
        }
      }
      __syncthreads();
      // ---- softmax over c (all 512 threads, 8x redundant rows) ----
      {
        const int r = t & 63, cq = t >> 6, b = r >> 4;
        float s[16];
#pragma unroll
        for (int cc = 0; cc < 16; ++cc) s[cc] = T_s[b * CC + cc] - sc_s[r][cc];
        float m = s[0];
#pragma unroll
        for (int cc = 1; cc < 16; ++cc) m = fmaxf(m, s[cc]);
        float den = 0.f;
#pragma unroll
        for (int cc = 0; cc < 16; ++cc) { s[cc] = __expf(s[cc] - m); den += s[cc]; }
        const float a = act_s[cap][r] / den;
#pragma unroll
        for (int k = 0; k < 2; ++k) {
          const int cc = 2 * cq + k;
          const float rh = fmaxf(s[cc] * a, 0.01f);
          rh2[cc][r] = rh;
          atomicAdd(&sr_s[cap][b * CC + cc], rh);
        }
      }
      __syncthreads();
    }

    // ---- phase B: S1/S2 ----
#pragma unroll
    for (int pair = 0; pair < 2; ++pair) {
      ABfrag A;
      const int r = pair * 32 + ln31;
      A.h[0] = *reinterpret_cast<const short4v*>(&pbf[cap][r][8 * h]);
      A.h[1] = *reinterpret_cast<const short4v*>(&pbf[cap][r][8 * h + 4]);
      float p1[4][2] = {}, p2[4][2] = {};
#pragma unroll
      for (int cl_ = 0; cl_ < 2; ++cl_) {
        float rq[16];
        if (PASS == 1) {
#pragma unroll
          for (int g = 0; g < 4; ++g) {
            const float4 v = *reinterpret_cast<const float4*>(
                &rh2[cbase + cl_][pair * 32 + 8 * g + 4 * h]);
            rq[4 * g + 0] = v.x; rq[4 * g + 1] = v.y;
            rq[4 * g + 2] = v.z; rq[4 * g + 3] = v.w;
          }
        } else {
#pragma unroll
          for (int g = 0; g < 4; ++g) {
            const float4 v = *reinterpret_cast<const float4*>(
                &act_s[cap][pair * 32 + 8 * g + 4 * h]);
            rq[4 * g + 0] = fmaxf(v.x * 0.0625f, 0.01f);
            rq[4 * g + 1] = fmaxf(v.y * 0.0625f, 0.01f);
            rq[4 * g + 2] = fmaxf(v.z * 0.0625f, 0.01f);
            rq[4 * g + 3] = fmaxf(v.w * 0.0625f, 0.01f);
          }
        }
#pragma unroll
        for (int lh = 0; lh < 2; ++lh) {
          const f32x16 acc = __builtin_amdgcn_mfma_f32_32x32x16_bf16(
              A.v, wf[cl_ * 2 + lh], zero16, 0, 0, 0);
          const int t4 = cl_ * 2 + lh;
#pragma unroll
          for (int j = 0; j < 16; ++j) {
            const float v = acc[j];
            const float rv = rq[j] * v;
            p1[t4][j >> 3] += rv;
            p2[t4][j >> 3] = fmaf(rv, v, p2[t4][j >> 3]);
          }
        }
      }
#pragma unroll
      for (int t4 = 0; t4 < 4; ++t4)
#pragma unroll
        for (int bh = 0; bh < 2; ++bh) {
          float v1 = p1[t4][bh]; v1 += __shfl_xor(v1, 32, 64);
          float v2 = p2[t4][bh]; v2 += __shfl_xor(v2, 32, 64);
          const int b = pair * 2 + bh, c = cbase + (t4 >> 1);
          const int idx = (b * CC + c) * LV + (t4 & 1) * 32 + ln31;
          if (STORE) {
            if (h == 0) { S1p[idx] = v1; S2p[idx] = v2; }
          } else if (h == 0) {
            atomicAdd(&S1p[idx], v1); atomicAdd(&S2p[idx], v2);
          }
        }
    }

    // ---- Sr ----
    if (PASS == 1) {
      if (t < 64) {
        if (STORE) Srp[t] = sr_s[cap][t];
        else atomicAdd(&Srp[t], sr_s[cap][t]);
      }
    } else {
      if (t < 64) {
        const int b = t >> 4;
        float s = 0.f;
#pragma unroll
        for (int xy = 0; xy < 16; ++xy)
          s += fmaxf(act_s[cap][b * 16 + xy] * 0.0625f, 0.01f);
        if (STORE) Srp[t] = s; else atomicAdd(&Srp[t], s);
      }
    }

    // ---- convert prefetched cap1 W at the boundary ----
    if (cap == 0) {
#pragma unroll
      for (int k = 0; k < 4; ++k) wf[k] = cvt8(wraw[2 * k], wraw[2 * k + 1]);
#pragma unroll
      for (int k = 0; k < 4; ++k) asm volatile("" : "+v"(wf[k]));
      if (PASS == 1) __syncthreads();  // order cap1 sc_s writes vs cap0 softmax reads
    }
  }
}

__global__ void reduce_slabs(const float* __restrict__ Spart, float* __restrict__ Sred,
                             int nslab, int chunk) {
  const int idx = blockIdx.x * 256 + threadIdx.x;
  if (idx >= SLABTOT) return;
  const int s0 = blockIdx.y * chunk;
  const int s1 = min(s0 + chunk, nslab);
  float a = 0.f;
#pragma unroll 8
  for (int s = s0; s < s1; s++) a += Spart[(size_t)s * SLABTOT + idx];
  atomicAdd(&Sred[idx], a);
}

template <int FINAL>
__global__ void stats_post(const float* __restrict__ Sred,
                           const float* __restrict__ beta_v,
                           const float* __restrict__ beta_a,
                           const float* __restrict__ lam,
                           float* __restrict__ mu_out, float* __restrict__ T_out,
                           float* __restrict__ out) {
  const int t = threadIdx.x;
  if (t >= 64) return;
  const int b = t >> 4, c = t & 15;
  const float* S1 = Sred;
  const float* S2 = Sred + SLAB;
  const float sr = Sred[2 * SLAB + b * CC + c];
  const float inv = 1.f / sr;
  const float bv = beta_v[0];
  float csum = 0.f, lsum = 0.f;
  for (int l = 0; l < LV; l++) {
    const int idx = (b * CC + c) * LV + l;
    const float m = S1[idx] * inv;
    float s2 = S2[idx] * inv - m * m;
    s2 = fmaxf(s2, 0.01f);
    const float ls = logf(s2);
    csum += bv + ls;
    lsum += ls;
    if (FINAL) out[(size_t)b * 1040 + c * LV + l] = m;
    else mu_out[idx] = m;
  }
  const float z = lam[0] * (beta_a[c] - csum * sr);
  const float ac = 1.f / (1.f + expf(-z));
  if (FINAL) out[(size_t)b * 1040 + 1024 + c] = ac;
  else T_out[b * CC + c] = logf(ac) - 0.5f * (64.f * LOG_2PI_F + lsum);
}

extern "C" void kernel_launch(void* const* d_in, const int* in_sizes, int n_in,
                              void* d_out, int out_size, void* d_ws, size_t ws_size,
                              hipStream_t stream) {
  const float* x = (const float*)d_in[0];
  const float* W = (const float*)d_in[1];
  const float* beta_v = (const float*)d_in[2];
  const float* beta_a = (const float*)d_in[3];
  const float* lam = (const float*)d_in[4];
  float* out = (float*)d_out;

  const size_t need = ((size_t)BC * SLABTOT + SLABTOT + SLAB + 64) * sizeof(float);
  const int nslab = (ws_size >= need) ? BC : NSLAB_SM;
  const bool store = (nslab == BC);

  float* Spart = (float*)d_ws;
  float* Sred = Spart + (size_t)nslab * SLABTOT;
  float* muW = Sred + SLABTOT;
  float* Tw = muW + SLAB;

  const int chunk = 32;
  const dim3 rgrid((SLABTOT + 255) / 256, (nslab + chunk - 1) / chunk);

  // ---- pass 0 ----
  if (!store) hipMemsetAsync(Spart, 0, (size_t)nslab * SLABTOT * sizeof(float), stream);
  hipMemsetAsync(Sred, 0, SLABTOT * sizeof(float), stream);
  if (store) em_sweep2<0, 1><<<dim3(512), dim3(512), 0, stream>>>(x, W, nullptr, nullptr, Spart, nslab);
  else       em_sweep2<0, 0><<<dim3(512), dim3(512), 0, stream>>>(x, W, nullptr, nullptr, Spart, nslab);
  reduce_slabs<<<rgrid, dim3(256), 0, stream>>>(Spart, Sred, nslab, chunk);
  stats_post<0><<<dim3(1), dim3(64), 0, stream>>>(Sred, beta_v, beta_a, lam, muW, Tw, nullptr);

  // ---- pass 1 ----
  if (!store) hipMemsetAsync(Spart, 0, (size_t)nslab * SLABTOT * sizeof(float), stream);
  hipMemsetAsync(Sred, 0, SLABTOT * sizeof(float), stream);
  if (store) em_sweep2<1, 1><<<dim3(512), dim3(512), 0, stream>>>(x, W, muW, Tw, Spart, nslab);
  else       em_sweep2<1, 0><<<dim3(512), dim3(512), 0, stream>>>(x, W, muW, Tw, Spart, nslab);
  reduce_slabs<<<rgrid, dim3(256), 0, stream>>>(Spart, Sred, nslab, chunk);
  stats_post<1><<<dim3(1), dim3(64), 0, stream>>>(Sred, beta_v, beta_a, lam, nullptr, nullptr, out);
}

// Round 10
// 116.155 us; speedup vs baseline: 6.7086x; 1.3277x over previous
//
#include <hip/hip_runtime.h>

#define LOG_2PI_F 1.8378770664093453f

constexpr int BC = 1024, CC = 16, PV = 16, LV = 64, BB = 4;
constexpr int CH = (PV + 1) * BC;
constexpr int SLAB = BB * CC * LV;           // 4096
constexpr int SLABTOT = 2 * SLAB + BB * CC;  // 8256
constexpr int NSLAB_SM = 32;
constexpr size_t WBF_ELEMS = (size_t)CC * BC * LV * PV;   // 16.7M shorts
constexpr size_t POSE_ELEMS = (size_t)BC * 64 * 16;       // shorts
constexpr size_t ACT_ELEMS = (size_t)BC * 64;             // floats

typedef __attribute__((ext_vector_type(4))) short short4v;
typedef __attribute__((ext_vector_type(8))) short short8v;
typedef __attribute__((ext_vector_type(16))) float f32x16;

union ABfrag { short8v v; short4v h[2]; unsigned short u[8]; };

__device__ __forceinline__ unsigned short f2bf(float f) {
  unsigned u = __float_as_uint(f);
  u += 0x7fffu + ((u >> 16) & 1u);  // RNE
  return (unsigned short)(u >> 16);
}

__device__ __forceinline__ short8v cvt8(const float4 a, const float4 b) {
  ABfrag f;
  f.u[0] = f2bf(a.x); f.u[1] = f2bf(a.y); f.u[2] = f2bf(a.z); f.u[3] = f2bf(a.w);
  f.u[4] = f2bf(b.x); f.u[5] = f2bf(b.y); f.u[6] = f2bf(b.z); f.u[7] = f2bf(b.w);
  return f.v;
}

// One block per capsule i (grid 1024). 8 waves; wave w owns c = 2w..2w+1.
// MFMA v_mfma_f32_32x32x16_bf16: A m=lane&31,k=8h+j ; B n=lane&31,k=8h+j ;
// C/D col=lane&31, row=(reg&3)+8*(reg>>2)+4*h   [m74/m101 verified]
// W fragments: global->VGPR, converted IMMEDIATELY (the only spill-proof
// pattern: rounds 4/8/9 all spilled when raw loads were held across compute).
// CACHE=1: PASS0 persists bf16 W-frags + pose-bf16 + act to ws; PASS1 reads
// them back (half the W bytes, zero conversion VALU, no x access).
template <int PASS, int STORE, int CACHE>
__global__ __launch_bounds__(512, 4) void em_sweep(
    const float* __restrict__ x, const float* __restrict__ W,
    const float* __restrict__ mu, const float* __restrict__ T,
    float* __restrict__ Spart, int nslab,
    unsigned short* __restrict__ WbfC, unsigned short* __restrict__ poseC,
    float* __restrict__ actC) {
  const int i = blockIdx.x, t = threadIdx.x;
  const int w = t >> 6, lane = t & 63;
  const int ln31 = lane & 31, h = lane >> 5;
  const int cbase = 2 * w;

  float* S1p = Spart + (size_t)(i % nslab) * SLABTOT;
  float* S2p = S1p + SLAB;
  float* Srp = S1p + 2 * SLAB;

  __shared__ __align__(16) unsigned short pbf[64][20];  // pitch 40B: 2-way banks
  __shared__ float act_s[64];
  __shared__ float T_s[64];
  __shared__ float sr_s[64];
  __shared__ float sc_s[64][17];
  __shared__ float rh2[16][64];

  // ---- W -> bf16 fragments in registers ----
  short8v wf[4];
  if (CACHE && PASS == 1) {
#pragma unroll
    for (int k = 0; k < 4; ++k) {
      const int cl_ = k >> 1, lh = k & 1;
      const size_t off = ((size_t)(cbase + cl_) * BC + i) * 1024 +
                         (lh * 32 + ln31) * 16 + 8 * h;
      wf[k] = *reinterpret_cast<const short8v*>(WbfC + off);
    }
  } else {
#pragma unroll
    for (int k = 0; k < 4; ++k) {
      const int cl_ = k >> 1, lh = k & 1;
      const float* src = W + ((size_t)(cbase + cl_) * BC + i) * 1024 +
                         (lh * 32 + ln31) * 16 + 8 * h;
      const float4 v0 = *reinterpret_cast<const float4*>(src);
      const float4 v1 = *reinterpret_cast<const float4*>(src + 4);
      wf[k] = cvt8(v0, v1);  // convert immediately (spill-proof)
    }
  }
#pragma unroll
  for (int k = 0; k < 4; ++k) asm volatile("" : "+v"(wf[k]));  // pin live

  // persist bf16 W-frags for the next sweep (coalesced 16B/lane stores)
  if (CACHE && PASS == 0) {
#pragma unroll
    for (int k = 0; k < 4; ++k) {
      const int cl_ = k >> 1, lh = k & 1;
      const size_t off = ((size_t)(cbase + cl_) * BC + i) * 1024 +
                         (lh * 32 + ln31) * 16 + 8 * h;
      *reinterpret_cast<short8v*>(WbfC + off) = wf[k];
    }
  }

  // ---- stage pose -> bf16 LDS, act -> f32 ----
  if (CACHE && PASS == 1) {
    if (t < 128) {  // clean 16B chunks, no scatter, no cvt
      const int r = t >> 1, half = t & 1;
      const int4 v = *reinterpret_cast<const int4*>(
          poseC + ((size_t)i * 64 + r) * 16 + 8 * half);
      union { int4 q; short4v s[2]; } u;
      u.q = v;
      *reinterpret_cast<short4v*>(&pbf[r][8 * half]) = u.s[0];
      *reinterpret_cast<short4v*>(&pbf[r][8 * half + 4]) = u.s[1];
    }
    if (t < 64) {
      act_s[t] = actC[(size_t)i * 64 + t];
      T_s[t] = T[t];
      sr_s[t] = 0.f;
    }
  } else {
    if (t < 256) {
      const int b = t >> 6, p = (t >> 2) & 15, q = t & 3;
      const float4 v = *reinterpret_cast<const float4*>(
          x + ((size_t)(b * CH + p * BC + i)) * 16 + 4 * q);
      pbf[b * 16 + 4 * q + 0][p] = f2bf(v.x);
      pbf[b * 16 + 4 * q + 1][p] = f2bf(v.y);
      pbf[b * 16 + 4 * q + 2][p] = f2bf(v.z);
      pbf[b * 16 + 4 * q + 3][p] = f2bf(v.w);
    }
    if (t < 64) {
      const int b = t >> 4, xy = t & 15;
      const float a = x[((size_t)(b * CH + PV * BC + i)) * 16 + xy];
      act_s[t] = a;
      if (CACHE && PASS == 0) actC[(size_t)i * 64 + t] = a;
      if (PASS == 1) { T_s[t] = T[t]; sr_s[t] = 0.f; }
    }
  }

  float mur[2][2][4];  // [c_local][lh][b], per-lane l = lh*32 + ln31
  if (PASS == 1) {
#pragma unroll
    for (int cl_ = 0; cl_ < 2; ++cl_)
#pragma unroll
      for (int lh = 0; lh < 2; ++lh)
#pragma unroll
        for (int b = 0; b < 4; ++b)
          mur[cl_][lh][b] = mu[(b * CC + cbase + cl_) * LV + lh * 32 + ln31];
  }
  __syncthreads();

  // persist pose-bf16 for the next sweep (reads LDS after barrier)
  if (CACHE && PASS == 0) {
    if (t < 128) {
      const int r = t >> 1, half = t & 1;
      union { int4 q; short4v s[2]; } u;
      u.s[0] = *reinterpret_cast<const short4v*>(&pbf[r][8 * half]);
      u.s[1] = *reinterpret_cast<const short4v*>(&pbf[r][8 * half + 4]);
      *reinterpret_cast<int4*>(poseC + ((size_t)i * 64 + r) * 16 + 8 * half) = u.q;
    }
  }

  const f32x16 zero16 = {};

  if (PASS == 1) {
    // ---- phase A: scores ----
#pragma unroll
    for (int pair = 0; pair < 2; ++pair) {
      ABfrag A;
      {
        const int r = pair * 32 + ln31;
        A.h[0] = *reinterpret_cast<const short4v*>(&pbf[r][8 * h]);
        A.h[1] = *reinterpret_cast<const short4v*>(&pbf[r][8 * h + 4]);
      }
#pragma unroll
      for (int cl_ = 0; cl_ < 2; ++cl_) {
        float scv[16];
#pragma unroll
        for (int j = 0; j < 16; ++j) scv[j] = 0.f;
#pragma unroll
        for (int lh = 0; lh < 2; ++lh) {
          const f32x16 acc = __builtin_amdgcn_mfma_f32_32x32x16_bf16(
              A.v, wf[cl_ * 2 + lh], zero16, 0, 0, 0);
#pragma unroll
          for (int j = 0; j < 16; ++j) {
            const float d = acc[j] - mur[cl_][lh][pair * 2 + (j >> 3)];
            scv[j] = fmaf(d, d, scv[j]);
          }
        }
#pragma unroll
        for (int j = 0; j < 16; ++j) {  // sum over 32 cols (within half-wave)
          float v = scv[j];
          v += __shfl_xor(v, 1, 64);  v += __shfl_xor(v, 2, 64);
          v += __shfl_xor(v, 4, 64);  v += __shfl_xor(v, 8, 64);
          v += __shfl_xor(v, 16, 64);
          if (ln31 == 0)
            sc_s[pair * 32 + (j & 3) + 8 * (j >> 2) + 4 * h][cbase + cl_] = v;
        }
      }
    }
    __syncthreads();
    // ---- softmax over c (all 512 threads, 8x redundant rows) ----
    {
      const int r = t & 63, cq = t >> 6, b = r >> 4;
      float s[16];
#pragma unroll
      for (int cc = 0; cc < 16; ++cc) s[cc] = T_s[b * CC + cc] - sc_s[r][cc];
      float m = s[0];
#pragma unroll
      for (int cc = 1; cc < 16; ++cc) m = fmaxf(m, s[cc]);
      float den = 0.f;
#pragma unroll
      for (int cc = 0; cc < 16; ++cc) { s[cc] = __expf(s[cc] - m); den += s[cc]; }
      const float a = act_s[r] / den;
#pragma unroll
      for (int k = 0; k < 2; ++k) {
        const int cc = 2 * cq + k;
        const float rh = fmaxf(s[cc] * a, 0.01f);
        rh2[cc][r] = rh;
        atomicAdd(&sr_s[b * CC + cc], rh);
      }
    }
    __syncthreads();
  }

  // ---- phase B: S1/S2 ----
#pragma unroll
  for (int pair = 0; pair < 2; ++pair) {
    ABfrag A;
    {
      const int r = pair * 32 + ln31;
      A.h[0] = *reinterpret_cast<const short4v*>(&pbf[r][8 * h]);
      A.h[1] = *reinterpret_cast<const short4v*>(&pbf[r][8 * h + 4]);
    }
    float p1[4][2] = {}, p2[4][2] = {};
#pragma unroll
    for (int cl_ = 0; cl_ < 2; ++cl_) {
      float rq[16];
      if (PASS == 1) {
#pragma unroll
        for (int g = 0; g < 4; ++g) {
          const float4 v = *reinterpret_cast<const float4*>(
              &rh2[cbase + cl_][pair * 32 + 8 * g + 4 * h]);
          rq[4 * g + 0] = v.x; rq[4 * g + 1] = v.y;
          rq[4 * g + 2] = v.z; rq[4 * g + 3] = v.w;
        }
      } else {
#pragma unroll
        for (int g = 0; g < 4; ++g) {
          const float4 v = *reinterpret_cast<const float4*>(
              &act_s[pair * 32 + 8 * g + 4 * h]);
          rq[4 * g + 0] = fmaxf(v.x * 0.0625f, 0.01f);
          rq[4 * g + 1] = fmaxf(v.y * 0.0625f, 0.01f);
          rq[4 * g + 2] = fmaxf(v.z * 0.0625f, 0.01f);
          rq[4 * g + 3] = fmaxf(v.w * 0.0625f, 0.01f);
        }
      }
#pragma unroll
      for (int lh = 0; lh < 2; ++lh) {
        const f32x16 acc = __builtin_amdgcn_mfma_f32_32x32x16_bf16(
            A.v, wf[cl_ * 2 + lh], zero16, 0, 0, 0);
        const int t4 = cl_ * 2 + lh;
#pragma unroll
        for (int j = 0; j < 16; ++j) {
          const float v = acc[j];
          const float rv = rq[j] * v;
          p1[t4][j >> 3] += rv;
          p2[t4][j >> 3] = fmaf(rv, v, p2[t4][j >> 3]);
        }
      }
    }
#pragma unroll
    for (int t4 = 0; t4 < 4; ++t4)
#pragma unroll
      for (int bh = 0; bh < 2; ++bh) {
        float v1 = p1[t4][bh]; v1 += __shfl_xor(v1, 32, 64);
        float v2 = p2[t4][bh]; v2 += __shfl_xor(v2, 32, 64);
        const int b = pair * 2 + bh, c = cbase + (t4 >> 1);
        const int idx = (b * CC + c) * LV + (t4 & 1) * 32 + ln31;
        if (STORE) {
          if (h == 0) { S1p[idx] = v1; S2p[idx] = v2; }
        } else if (h == 0) {
          atomicAdd(&S1p[idx], v1); atomicAdd(&S2p[idx], v2);
        }
      }
  }

  // ---- Sr ----
  if (PASS == 1) {
    if (t < 64) { if (STORE) Srp[t] = sr_s[t]; else atomicAdd(&Srp[t], sr_s[t]); }
  } else {
    if (t < 64) {
      const int b = t >> 4;
      float s = 0.f;
#pragma unroll
      for (int xy = 0; xy < 16; ++xy) s += fmaxf(act_s[b * 16 + xy] * 0.0625f, 0.01f);
      if (STORE) Srp[t] = s; else atomicAdd(&Srp[t], s);
    }
  }
}

__global__ void reduce_slabs(const float* __restrict__ Spart, float* __restrict__ Sred,
                             int nslab, int chunk) {
  const int idx = blockIdx.x * 256 + threadIdx.x;
  if (idx >= SLABTOT) return;
  const int s0 = blockIdx.y * chunk;
  const int s1 = min(s0 + chunk, nslab);
  float a = 0.f;
#pragma unroll 8
  for (int s = s0; s < s1; s++) a += Spart[(size_t)s * SLABTOT + idx];
  atomicAdd(&Sred[idx], a);
}

template <int FINAL>
__global__ void stats_post(const float* __restrict__ Sred,
                           const float* __restrict__ beta_v,
                           const float* __restrict__ beta_a,
                           const float* __restrict__ lam,
                           float* __restrict__ mu_out, float* __restrict__ T_out,
                           float* __restrict__ out) {
  const int t = threadIdx.x;
  if (t >= 64) return;
  const int b = t >> 4, c = t & 15;
  const float* S1 = Sred;
  const float* S2 = Sred + SLAB;
  const float sr = Sred[2 * SLAB + b * CC + c];
  const float inv = 1.f / sr;
  const float bv = beta_v[0];
  float csum = 0.f, lsum = 0.f;
  for (int l = 0; l < LV; l++) {
    const int idx = (b * CC + c) * LV + l;
    const float m = S1[idx] * inv;
    float s2 = S2[idx] * inv - m * m;
    s2 = fmaxf(s2, 0.01f);
    const float ls = logf(s2);
    csum += bv + ls;
    lsum += ls;
    if (FINAL) out[(size_t)b * 1040 + c * LV + l] = m;
    else mu_out[idx] = m;
  }
  const float z = lam[0] * (beta_a[c] - csum * sr);
  const float ac = 1.f / (1.f + expf(-z));
  if (FINAL) out[(size_t)b * 1040 + 1024 + c] = ac;
  else T_out[b * CC + c] = logf(ac) - 0.5f * (64.f * LOG_2PI_F + lsum);
}

extern "C" void kernel_launch(void* const* d_in, const int* in_sizes, int n_in,
                              void* d_out, int out_size, void* d_ws, size_t ws_size,
                              hipStream_t stream) {
  const float* x = (const float*)d_in[0];
  const float* W = (const float*)d_in[1];
  const float* beta_v = (const float*)d_in[2];
  const float* beta_a = (const float*)d_in[3];
  const float* lam = (const float*)d_in[4];
  float* out = (float*)d_out;

  const size_t base_floats = (size_t)BC * SLABTOT + SLABTOT + SLAB + 64;
  const size_t need_store = base_floats * sizeof(float);
  const size_t need_cache = need_store + WBF_ELEMS * 2 + POSE_ELEMS * 2 +
                            ACT_ELEMS * sizeof(float);

  const bool cache = (ws_size >= need_cache);
  const int nslab = (ws_size >= need_store) ? BC : NSLAB_SM;
  const bool store = (nslab == BC);

  float* Spart = (float*)d_ws;
  float* Sred = Spart + (size_t)nslab * SLABTOT;
  float* muW = Sred + SLABTOT;
  float* Tw = muW + SLAB;
  unsigned short* WbfC = (unsigned short*)(Tw + 64);
  unsigned short* poseC = WbfC + WBF_ELEMS;
  float* actC = (float*)(poseC + POSE_ELEMS);

  const int chunk = 32;
  const dim3 rgrid((SLABTOT + 255) / 256, (nslab + chunk - 1) / chunk);

  // ---- pass 0 ----
  if (!store) hipMemsetAsync(Spart, 0, (size_t)nslab * SLABTOT * sizeof(float), stream);
  hipMemsetAsync(Sred, 0, SLABTOT * sizeof(float), stream);
  if (cache)
    em_sweep<0, 1, 1><<<dim3(BC), dim3(512), 0, stream>>>(x, W, nullptr, nullptr, Spart, nslab, WbfC, poseC, actC);
  else if (store)
    em_sweep<0, 1, 0><<<dim3(BC), dim3(512), 0, stream>>>(x, W, nullptr, nullptr, Spart, nslab, nullptr, nullptr, nullptr);
  else
    em_sweep<0, 0, 0><<<dim3(BC), dim3(512), 0, stream>>>(x, W, nullptr, nullptr, Spart, nslab, nullptr, nullptr, nullptr);
  reduce_slabs<<<rgrid, dim3(256), 0, stream>>>(Spart, Sred, nslab, chunk);
  stats_post<0><<<dim3(1), dim3(64), 0, stream>>>(Sred, beta_v, beta_a, lam, muW, Tw, nullptr);

  // ---- pass 1 ----
  if (!store) hipMemsetAsync(Spart, 0, (size_t)nslab * SLABTOT * sizeof(float), stream);
  hipMemsetAsync(Sred, 0, SLABTOT * sizeof(float), stream);
  if (cache)
    em_sweep<1, 1, 1><<<dim3(BC), dim3(512), 0, stream>>>(x, W, muW, Tw, Spart, nslab, WbfC, poseC, actC);
  else if (store)
    em_sweep<1, 1, 0><<<dim3(BC), dim3(512), 0, stream>>>(x, W, muW, Tw, Spart, nslab, nullptr, nullptr, nullptr);
  else
    em_sweep<1, 0, 0><<<dim3(BC), dim3(512), 0, stream>>>(x, W, muW, Tw, Spart, nslab, nullptr, nullptr, nullptr);
  reduce_slabs<<<rgrid, dim3(256), 0, stream>>>(Spart, Sred, nslab, chunk);
  stats_post<1><<<dim3(1), dim3(64), 0, stream>>>(Sred, beta_v, beta_a, lam, nullptr, nullptr, out);
}

// Round 11
// 91.076 us; speedup vs baseline: 8.5559x; 1.2754x over previous
//
#include <hip/hip_runtime.h>

#define LOG_2PI_F 1.8378770664093453f

constexpr int BC = 1024, CC = 16, PV = 16, LV = 64, BB = 4;
constexpr int CH = (PV + 1) * BC;
constexpr int SLAB = BB * CC * LV;           // 4096
constexpr int SLABTOT = 2 * SLAB + BB * CC;  // 8256
constexpr int NSLAB_SM = 32;
constexpr size_t WBF_ELEMS = (size_t)CC * BC * LV * PV;   // 16.7M shorts
constexpr size_t POSE_ELEMS = (size_t)BC * 64 * 16;       // shorts
constexpr size_t ACT_ELEMS = (size_t)BC * 64;             // floats

typedef __attribute__((ext_vector_type(4))) short short4v;
typedef __attribute__((ext_vector_type(8))) short short8v;
typedef __attribute__((ext_vector_type(16))) float f32x16;

union ABfrag { short8v v; short4v h[2]; unsigned short u[8]; };

__device__ __forceinline__ unsigned short f2bf(float f) {
  unsigned u = __float_as_uint(f);
  u += 0x7fffu + ((u >> 16) & 1u);  // RNE
  return (unsigned short)(u >> 16);
}

__device__ __forceinline__ short8v cvt8(const float4 a, const float4 b) {
  ABfrag f;
  f.u[0] = f2bf(a.x); f.u[1] = f2bf(a.y); f.u[2] = f2bf(a.z); f.u[3] = f2bf(a.w);
  f.u[4] = f2bf(b.x); f.u[5] = f2bf(b.y); f.u[6] = f2bf(b.z); f.u[7] = f2bf(b.w);
  return f.v;
}

// One block per capsule i (grid 1024). 8 waves; wave w owns c = 2w..2w+1.
// MFMA v_mfma_f32_32x32x16_bf16: A m=lane&31,k=8h+j ; B n=lane&31,k=8h+j ;
// C/D col=lane&31, row=(reg&3)+8*(reg>>2)+4*h   [m74/m101 verified]
// A/B fragment layouts are IDENTICAL -> phase A uses mfma(W, pose) (D[l][r]:
// lane=r, regs=l) so the l-sum of (V-mu)^2 is in-register + ONE shfl_xor(32),
// replacing 320 shfl + 320 add per thread. Phase B keeps mfma(pose, W)
// (D[r][l]: lane=l, regs=r) so the rhat-weighted r-sum stays in-register.
// W fragments: global->VGPR, converted IMMEDIATELY (rounds 4/8/9: holding raw
// loads across compute spills). CACHE=1: PASS0 persists bf16 W/pose/act to ws.
template <int PASS, int STORE, int CACHE>
__global__ __launch_bounds__(512, 4) void em_sweep(
    const float* __restrict__ x, const float* __restrict__ W,
    const float* __restrict__ mu, const float* __restrict__ T,
    float* __restrict__ Spart, int nslab,
    unsigned short* __restrict__ WbfC, unsigned short* __restrict__ poseC,
    float* __restrict__ actC) {
  const int i = blockIdx.x, t = threadIdx.x;
  const int w = t >> 6, lane = t & 63;
  const int ln31 = lane & 31, h = lane >> 5;
  const int cbase = 2 * w;

  float* S1p = Spart + (size_t)(i % nslab) * SLABTOT;
  float* S2p = S1p + SLAB;
  float* Srp = S1p + 2 * SLAB;

  __shared__ __align__(16) unsigned short pbf[64][20];  // pitch 40B: 2-way banks
  __shared__ float act_s[64];
  __shared__ float T_s[64];
  __shared__ float sr_s[64];
  __shared__ float sc_s[64][17];
  __shared__ float rh2[16][64];
  __shared__ __align__(16) float mu_s[64][64];  // [b*CC+c][l], broadcast reads

  // ---- W -> bf16 fragments in registers ----
  short8v wf[4];
  if (CACHE && PASS == 1) {
#pragma unroll
    for (int k = 0; k < 4; ++k) {
      const int cl_ = k >> 1, lh = k & 1;
      const size_t off = ((size_t)(cbase + cl_) * BC + i) * 1024 +
                         (lh * 32 + ln31) * 16 + 8 * h;
      wf[k] = *reinterpret_cast<const short8v*>(WbfC + off);
    }
  } else {
#pragma unroll
    for (int k = 0; k < 4; ++k) {
      const int cl_ = k >> 1, lh = k & 1;
      const float* src = W + ((size_t)(cbase + cl_) * BC + i) * 1024 +
                         (lh * 32 + ln31) * 16 + 8 * h;
      const float4 v0 = *reinterpret_cast<const float4*>(src);
      const float4 v1 = *reinterpret_cast<const float4*>(src + 4);
      wf[k] = cvt8(v0, v1);  // convert immediately (spill-proof)
    }
  }
#pragma unroll
  for (int k = 0; k < 4; ++k) asm volatile("" : "+v"(wf[k]));  // pin live

  // persist bf16 W-frags for the next sweep (coalesced 16B/lane stores)
  if (CACHE && PASS == 0) {
#pragma unroll
    for (int k = 0; k < 4; ++k) {
      const int cl_ = k >> 1, lh = k & 1;
      const size_t off = ((size_t)(cbase + cl_) * BC + i) * 1024 +
                         (lh * 32 + ln31) * 16 + 8 * h;
      *reinterpret_cast<short8v*>(WbfC + off) = wf[k];
    }
  }

  // ---- stage pose -> bf16 LDS, act -> f32, mu -> LDS (PASS1) ----
  if (CACHE && PASS == 1) {
    if (t < 128) {  // clean 16B chunks, no scatter, no cvt
      const int r = t >> 1, half = t & 1;
      const int4 v = *reinterpret_cast<const int4*>(
          poseC + ((size_t)i * 64 + r) * 16 + 8 * half);
      union { int4 q; short4v s[2]; } u;
      u.q = v;
      *reinterpret_cast<short4v*>(&pbf[r][8 * half]) = u.s[0];
      *reinterpret_cast<short4v*>(&pbf[r][8 * half + 4]) = u.s[1];
    }
    if (t < 64) {
      act_s[t] = actC[(size_t)i * 64 + t];
      T_s[t] = T[t];
      sr_s[t] = 0.f;
    }
  } else {
    if (t < 256) {
      const int b = t >> 6, p = (t >> 2) & 15, q = t & 3;
      const float4 v = *reinterpret_cast<const float4*>(
          x + ((size_t)(b * CH + p * BC + i)) * 16 + 4 * q);
      pbf[b * 16 + 4 * q + 0][p] = f2bf(v.x);
      pbf[b * 16 + 4 * q + 1][p] = f2bf(v.y);
      pbf[b * 16 + 4 * q + 2][p] = f2bf(v.z);
      pbf[b * 16 + 4 * q + 3][p] = f2bf(v.w);
    }
    if (t < 64) {
      const int b = t >> 4, xy = t & 15;
      const float a = x[((size_t)(b * CH + PV * BC + i)) * 16 + xy];
      act_s[t] = a;
      if (CACHE && PASS == 0) actC[(size_t)i * 64 + t] = a;
      if (PASS == 1) { T_s[t] = T[t]; sr_s[t] = 0.f; }
    }
  }
  if (PASS == 1) {  // stage mu: 4096 floats, coalesced float4
    const float4* msrc = reinterpret_cast<const float4*>(mu);
    float4* mdst = reinterpret_cast<float4*>(&mu_s[0][0]);
    mdst[t] = msrc[t];
    mdst[t + 512] = msrc[t + 512];
  }
  __syncthreads();

  // persist pose-bf16 for the next sweep (reads LDS after barrier)
  if (CACHE && PASS == 0) {
    if (t < 128) {
      const int r = t >> 1, half = t & 1;
      union { int4 q; short4v s[2]; } u;
      u.s[0] = *reinterpret_cast<const short4v*>(&pbf[r][8 * half]);
      u.s[1] = *reinterpret_cast<const short4v*>(&pbf[r][8 * half + 4]);
      *reinterpret_cast<int4*>(poseC + ((size_t)i * 64 + r) * 16 + 8 * half) = u.q;
    }
  }

  const f32x16 zero16 = {};

  if (PASS == 1) {
    // ---- phase A (swapped): score(r,c) = sum_l (V-mu)^2, in-register ----
#pragma unroll
    for (int rowhalf = 0; rowhalf < 2; ++rowhalf) {
      ABfrag A;
      {
        const int r = rowhalf * 32 + ln31;
        A.h[0] = *reinterpret_cast<const short4v*>(&pbf[r][8 * h]);
        A.h[1] = *reinterpret_cast<const short4v*>(&pbf[r][8 * h + 4]);
      }
      const int b = (rowhalf * 32 + ln31) >> 4;
#pragma unroll
      for (int cl_ = 0; cl_ < 2; ++cl_) {
        float sc = 0.f;
#pragma unroll
        for (int lh = 0; lh < 2; ++lh) {
          // D[m=l][n=r]: lane col = r, regs = l
          const f32x16 acc = __builtin_amdgcn_mfma_f32_32x32x16_bf16(
              wf[cl_ * 2 + lh], A.v, zero16, 0, 0, 0);
          const float* mrow = &mu_s[b * CC + cbase + cl_][lh * 32 + 4 * h];
#pragma unroll
          for (int g = 0; g < 4; ++g) {  // l = lh*32 + 4h + 8g + k
            const float4 m4 = *reinterpret_cast<const float4*>(mrow + 8 * g);
            float d;
            d = acc[4 * g + 0] - m4.x; sc = fmaf(d, d, sc);
            d = acc[4 * g + 1] - m4.y; sc = fmaf(d, d, sc);
            d = acc[4 * g + 2] - m4.z; sc = fmaf(d, d, sc);
            d = acc[4 * g + 3] - m4.w; sc = fmaf(d, d, sc);
          }
        }
        sc += __shfl_xor(sc, 32, 64);  // combine h halves (l+-4 groups)
        if (h == 0) sc_s[rowhalf * 32 + ln31][cbase + cl_] = sc;
      }
    }
    __syncthreads();
    // ---- softmax over c (all 512 threads, 8x redundant rows) ----
    {
      const int r = t & 63, cq = t >> 6, b = r >> 4;
      float s[16];
#pragma unroll
      for (int cc = 0; cc < 16; ++cc) s[cc] = T_s[b * CC + cc] - sc_s[r][cc];
      float m = s[0];
#pragma unroll
      for (int cc = 1; cc < 16; ++cc) m = fmaxf(m, s[cc]);
      float den = 0.f;
#pragma unroll
      for (int cc = 0; cc < 16; ++cc) { s[cc] = __expf(s[cc] - m); den += s[cc]; }
      const float a = act_s[r] / den;
#pragma unroll
      for (int k = 0; k < 2; ++k) {
        const int cc = 2 * cq + k;
        const float rh = fmaxf(s[cc] * a, 0.01f);
        rh2[cc][r] = rh;
        atomicAdd(&sr_s[b * CC + cc], rh);
      }
    }
    __syncthreads();
  }

  // ---- phase B: S1/S2 (original orientation; r-sum in-register) ----
#pragma unroll
  for (int pair = 0; pair < 2; ++pair) {
    ABfrag A;
    {
      const int r = pair * 32 + ln31;
      A.h[0] = *reinterpret_cast<const short4v*>(&pbf[r][8 * h]);
      A.h[1] = *reinterpret_cast<const short4v*>(&pbf[r][8 * h + 4]);
    }
    float p1[4][2] = {}, p2[4][2] = {};
#pragma unroll
    for (int cl_ = 0; cl_ < 2; ++cl_) {
      float rq[16];
      if (PASS == 1) {
#pragma unroll
        for (int g = 0; g < 4; ++g) {
          const float4 v = *reinterpret_cast<const float4*>(
              &rh2[cbase + cl_][pair * 32 + 8 * g + 4 * h]);
          rq[4 * g + 0] = v.x; rq[4 * g + 1] = v.y;
          rq[4 * g + 2] = v.z; rq[4 * g + 3] = v.w;
        }
      } else {
#pragma unroll
        for (int g = 0; g < 4; ++g) {
          const float4 v = *reinterpret_cast<const float4*>(
              &act_s[pair * 32 + 8 * g + 4 * h]);
          rq[4 * g + 0] = fmaxf(v.x * 0.0625f, 0.01f);
          rq[4 * g + 1] = fmaxf(v.y * 0.0625f, 0.01f);
          rq[4 * g + 2] = fmaxf(v.z * 0.0625f, 0.01f);
          rq[4 * g + 3] = fmaxf(v.w * 0.0625f, 0.01f);
        }
      }
#pragma unroll
      for (int lh = 0; lh < 2; ++lh) {
        const f32x16 acc = __builtin_amdgcn_mfma_f32_32x32x16_bf16(
            A.v, wf[cl_ * 2 + lh], zero16, 0, 0, 0);
        const int t4 = cl_ * 2 + lh;
#pragma unroll
        for (int j = 0; j < 16; ++j) {
          const float v = acc[j];
          const float rv = rq[j] * v;
          p1[t4][j >> 3] += rv;
          p2[t4][j >> 3] = fmaf(rv, v, p2[t4][j >> 3]);
        }
      }
    }
#pragma unroll
    for (int t4 = 0; t4 < 4; ++t4)
#pragma unroll
      for (int bh = 0; bh < 2; ++bh) {
        float v1 = p1[t4][bh]; v1 += __shfl_xor(v1, 32, 64);
        float v2 = p2[t4][bh]; v2 += __shfl_xor(v2, 32, 64);
        const int b = pair * 2 + bh, c = cbase + (t4 >> 1);
        const int idx = (b * CC + c) * LV + (t4 & 1) * 32 + ln31;
        if (STORE) {
          if (h == 0) { S1p[idx] = v1; S2p[idx] = v2; }
        } else if (h == 0) {
          atomicAdd(&S1p[idx], v1); atomicAdd(&S2p[idx], v2);
        }
      }
  }

  // ---- Sr ----
  if (PASS == 1) {
    if (t < 64) { if (STORE) Srp[t] = sr_s[t]; else atomicAdd(&Srp[t], sr_s[t]); }
  } else {
    if (t < 64) {
      const int b = t >> 4;
      float s = 0.f;
#pragma unroll
      for (int xy = 0; xy < 16; ++xy) s += fmaxf(act_s[b * 16 + xy] * 0.0625f, 0.01f);
      if (STORE) Srp[t] = s; else atomicAdd(&Srp[t], s);
    }
  }
}

__global__ void reduce_slabs(const float* __restrict__ Spart, float* __restrict__ Sred,
                             int nslab, int chunk) {
  const int idx = blockIdx.x * 256 + threadIdx.x;
  if (idx >= SLABTOT) return;
  const int s0 = blockIdx.y * chunk;
  const int s1 = min(s0 + chunk, nslab);
  float a = 0.f;
#pragma unroll 8
  for (int s = s0; s < s1; s++) a += Spart[(size_t)s * SLABTOT + idx];
  atomicAdd(&Sred[idx], a);
}

template <int FINAL>
__global__ void stats_post(const float* __restrict__ Sred,
                           const float* __restrict__ beta_v,
                           const float* __restrict__ beta_a,
                           const float* __restrict__ lam,
                           float* __restrict__ mu_out, float* __restrict__ T_out,
                           float* __restrict__ out) {
  const int t = threadIdx.x;
  if (t >= 64) return;
  const int b = t >> 4, c = t & 15;
  const float* S1 = Sred;
  const float* S2 = Sred + SLAB;
  const float sr = Sred[2 * SLAB + b * CC + c];
  const float inv = 1.f / sr;
  const float bv = beta_v[0];
  float csum = 0.f, lsum = 0.f;
  for (int l = 0; l < LV; l++) {
    const int idx = (b * CC + c) * LV + l;
    const float m = S1[idx] * inv;
    float s2 = S2[idx] * inv - m * m;
    s2 = fmaxf(s2, 0.01f);
    const float ls = logf(s2);
    csum += bv + ls;
    lsum += ls;
    if (FINAL) out[(size_t)b * 1040 + c * LV + l] = m;
    else mu_out[idx] = m;
  }
  const float z = lam[0] * (beta_a[c] - csum * sr);
  const float ac = 1.f / (1.f + expf(-z));
  if (FINAL) out[(size_t)b * 1040 + 1024 + c] = ac;
  else T_out[b * CC + c] = logf(ac) - 0.5f * (64.f * LOG_2PI_F + lsum);
}

extern "C" void kernel_launch(void* const* d_in, const int* in_sizes, int n_in,
                              void* d_out, int out_size, void* d_ws, size_t ws_size,
                              hipStream_t stream) {
  const float* x = (const float*)d_in[0];
  const float* W = (const float*)d_in[1];
  const float* beta_v = (const float*)d_in[2];
  const float* beta_a = (const float*)d_in[3];
  const float* lam = (const float*)d_in[4];
  float* out = (float*)d_out;

  const size_t base_floats = (size_t)BC * SLABTOT + SLABTOT + SLAB + 64;
  const size_t need_store = base_floats * sizeof(float);
  const size_t need_cache = need_store + WBF_ELEMS * 2 + POSE_ELEMS * 2 +
                            ACT_ELEMS * sizeof(float);

  const bool cache = (ws_size >= need_cache);
  const int nslab = (ws_size >= need_store) ? BC : NSLAB_SM;
  const bool store = (nslab == BC);

  float* Spart = (float*)d_ws;
  float* Sred = Spart + (size_t)nslab * SLABTOT;
  float* muW = Sred + SLABTOT;
  float* Tw = muW + SLAB;
  unsigned short* WbfC = (unsigned short*)(Tw + 64);
  unsigned short* poseC = WbfC + WBF_ELEMS;
  float* actC = (float*)(poseC + POSE_ELEMS);

  const int chunk = 32;
  const dim3 rgrid((SLABTOT + 255) / 256, (nslab + chunk - 1) / chunk);

  // ---- pass 0 ----
  if (!store) hipMemsetAsync(Spart, 0, (size_t)nslab * SLABTOT * sizeof(float), stream);
  hipMemsetAsync(Sred, 0, SLABTOT * sizeof(float), stream);
  if (cache)
    em_sweep<0, 1, 1><<<dim3(BC), dim3(512), 0, stream>>>(x, W, nullptr, nullptr, Spart, nslab, WbfC, poseC, actC);
  else if (store)
    em_sweep<0, 1, 0><<<dim3(BC), dim3(512), 0, stream>>>(x, W, nullptr, nullptr, Spart, nslab, nullptr, nullptr, nullptr);
  else
    em_sweep<0, 0, 0><<<dim3(BC), dim3(512), 0, stream>>>(x, W, nullptr, nullptr, Spart, nslab, nullptr, nullptr, nullptr);
  reduce_slabs<<<rgrid, dim3(256), 0, stream>>>(Spart, Sred, nslab, chunk);
  stats_post<0><<<dim3(1), dim3(64), 0, stream>>>(Sred, beta_v, beta_a, lam, muW, Tw, nullptr);

  // ---- pass 1 ----
  if (!store) hipMemsetAsync(Spart, 0, (size_t)nslab * SLABTOT * sizeof(float), stream);
  hipMemsetAsync(Sred, 0, SLABTOT * sizeof(float), stream);
  if (cache)
    em_sweep<1, 1, 1><<<dim3(BC), dim3(512), 0, stream>>>(x, W, muW, Tw, Spart, nslab, WbfC, poseC, actC);
  else if (store)
    em_sweep<1, 1, 0><<<dim3(BC), dim3(512), 0, stream>>>(x, W, muW, Tw, Spart, nslab, nullptr, nullptr, nullptr);
  else
    em_sweep<1, 0, 0><<<dim3(BC), dim3(512), 0, stream>>>(x, W, muW, Tw, Spart, nslab, nullptr, nullptr, nullptr);
  reduce_slabs<<<rgrid, dim3(256), 0, stream>>>(Spart, Sred, nslab, chunk);
  stats_post<1><<<dim3(1), dim3(64), 0, stream>>>(Sred, beta_v, beta_a, lam, nullptr, nullptr, out);
}

// Round 12
// 82.822 us; speedup vs baseline: 9.4086x; 1.0997x over previous
//
#include <hip/hip_runtime.h>

#define LOG_2PI_F 1.8378770664093453f

constexpr int BC = 1024, CC = 16, PV = 16, LV = 64, BB = 4;
constexpr int CH = (PV + 1) * BC;
constexpr int SLAB = BB * CC * LV;           // 4096
constexpr int SLABTOT = 2 * SLAB + BB * CC;  // 8256
constexpr int NSLAB_SM = 32;
constexpr size_t WBF_ELEMS = (size_t)CC * BC * LV * PV;   // 16.7M shorts
constexpr size_t POSE_ELEMS = (size_t)BC * 64 * 16;       // shorts
constexpr size_t ACT_ELEMS = (size_t)BC * 64;             // floats

typedef __attribute__((ext_vector_type(4))) short short4v;
typedef __attribute__((ext_vector_type(8))) short short8v;
typedef __attribute__((ext_vector_type(16))) float f32x16;

union ABfrag { short8v v; short4v h[2]; unsigned short u[8]; };

__device__ __forceinline__ unsigned short f2bf(float f) {
  unsigned u = __float_as_uint(f);
  u += 0x7fffu + ((u >> 16) & 1u);  // RNE
  return (unsigned short)(u >> 16);
}

__device__ __forceinline__ short8v cvt8(const float4 a, const float4 b) {
  ABfrag f;
  f.u[0] = f2bf(a.x); f.u[1] = f2bf(a.y); f.u[2] = f2bf(a.z); f.u[3] = f2bf(a.w);
  f.u[4] = f2bf(b.x); f.u[5] = f2bf(b.y); f.u[6] = f2bf(b.z); f.u[7] = f2bf(b.w);
  return f.v;
}

// One block per capsule i (grid 1024). 8 waves; wave w owns c = 2w..2w+1.
// MFMA v_mfma_f32_32x32x16_bf16: A m=lane&31,k=8h+j ; B n=lane&31,k=8h+j ;
// C/D col=lane&31, row=(reg&3)+8*(reg>>2)+4*h   [m74/m101 verified]
// Phase A uses SWAPPED mfma(W, pose) (D[l][r]) so the l-sum of (V-mu)^2 is
// in-register + one shfl_xor(32). Phase B keeps mfma(pose, W) (D[r][l]).
// W fragments: global->VGPR, converted IMMEDIATELY (rounds 4/8/9: holding raw
// loads across compute spills). CACHE=1: PASS0 persists bf16 W/pose/act to ws.
template <int PASS, int STORE, int CACHE>
__global__ __launch_bounds__(512, 4) void em_sweep(
    const float* __restrict__ x, const float* __restrict__ W,
    const float* __restrict__ mu, const float* __restrict__ T,
    float* __restrict__ Spart, int nslab,
    unsigned short* __restrict__ WbfC, unsigned short* __restrict__ poseC,
    float* __restrict__ actC) {
  const int i = blockIdx.x, t = threadIdx.x;
  const int w = t >> 6, lane = t & 63;
  const int ln31 = lane & 31, h = lane >> 5;
  const int cbase = 2 * w;

  float* S1p = Spart + (size_t)(i % nslab) * SLABTOT;
  float* S2p = S1p + SLAB;
  float* Srp = S1p + 2 * SLAB;

  __shared__ __align__(16) unsigned short pbf[64][20];  // pitch 40B: 2-way banks
  __shared__ float act_s[64];
  __shared__ float T_s[64];
  __shared__ float sr_s[64];
  __shared__ float sc_s[64][17];
  __shared__ float rh2[16][64];
  __shared__ __align__(16) float mu_s[64][64];  // [b*CC+c][l], broadcast reads

  // ---- W -> bf16 fragments in registers ----
  short8v wf[4];
  if (CACHE && PASS == 1) {
#pragma unroll
    for (int k = 0; k < 4; ++k) {
      const int cl_ = k >> 1, lh = k & 1;
      const size_t off = ((size_t)(cbase + cl_) * BC + i) * 1024 +
                         (lh * 32 + ln31) * 16 + 8 * h;
      wf[k] = *reinterpret_cast<const short8v*>(WbfC + off);
    }
  } else {
#pragma unroll
    for (int k = 0; k < 4; ++k) {
      const int cl_ = k >> 1, lh = k & 1;
      const float* src = W + ((size_t)(cbase + cl_) * BC + i) * 1024 +
                         (lh * 32 + ln31) * 16 + 8 * h;
      const float4 v0 = *reinterpret_cast<const float4*>(src);
      const float4 v1 = *reinterpret_cast<const float4*>(src + 4);
      wf[k] = cvt8(v0, v1);  // convert immediately (spill-proof)
    }
  }
#pragma unroll
  for (int k = 0; k < 4; ++k) asm volatile("" : "+v"(wf[k]));  // pin live

  // persist bf16 W-frags for the next sweep (coalesced 16B/lane stores)
  if (CACHE && PASS == 0) {
#pragma unroll
    for (int k = 0; k < 4; ++k) {
      const int cl_ = k >> 1, lh = k & 1;
      const size_t off = ((size_t)(cbase + cl_) * BC + i) * 1024 +
                         (lh * 32 + ln31) * 16 + 8 * h;
      *reinterpret_cast<short8v*>(WbfC + off) = wf[k];
    }
  }

  // ---- stage pose -> bf16 LDS, act -> f32, mu -> LDS (PASS1) ----
  if (CACHE && PASS == 1) {
    if (t < 128) {  // clean 16B chunks, no scatter, no cvt
      const int r = t >> 1, half = t & 1;
      const int4 v = *reinterpret_cast<const int4*>(
          poseC + ((size_t)i * 64 + r) * 16 + 8 * half);
      union { int4 q; short4v s[2]; } u;
      u.q = v;
      *reinterpret_cast<short4v*>(&pbf[r][8 * half]) = u.s[0];
      *reinterpret_cast<short4v*>(&pbf[r][8 * half + 4]) = u.s[1];
    }
    if (t < 64) {
      act_s[t] = actC[(size_t)i * 64 + t];
      T_s[t] = T[t];
      sr_s[t] = 0.f;
    }
  } else {
    if (t < 256) {
      const int b = t >> 6, p = (t >> 2) & 15, q = t & 3;
      const float4 v = *reinterpret_cast<const float4*>(
          x + ((size_t)(b * CH + p * BC + i)) * 16 + 4 * q);
      pbf[b * 16 + 4 * q + 0][p] = f2bf(v.x);
      pbf[b * 16 + 4 * q + 1][p] = f2bf(v.y);
      pbf[b * 16 + 4 * q + 2][p] = f2bf(v.z);
      pbf[b * 16 + 4 * q + 3][p] = f2bf(v.w);
    }
    if (t < 64) {
      const int b = t >> 4, xy = t & 15;
      const float a = x[((size_t)(b * CH + PV * BC + i)) * 16 + xy];
      act_s[t] = a;
      if (CACHE && PASS == 0) actC[(size_t)i * 64 + t] = a;
      if (PASS == 1) { T_s[t] = T[t]; sr_s[t] = 0.f; }
    }
  }
  if (PASS == 1) {  // stage mu: 4096 floats, coalesced float4
    const float4* msrc = reinterpret_cast<const float4*>(mu);
    float4* mdst = reinterpret_cast<float4*>(&mu_s[0][0]);
    mdst[t] = msrc[t];
    mdst[t + 512] = msrc[t + 512];
  }
  __syncthreads();

  // persist pose-bf16 for the next sweep (reads LDS after barrier)
  if (CACHE && PASS == 0) {
    if (t < 128) {
      const int r = t >> 1, half = t & 1;
      union { int4 q; short4v s[2]; } u;
      u.s[0] = *reinterpret_cast<const short4v*>(&pbf[r][8 * half]);
      u.s[1] = *reinterpret_cast<const short4v*>(&pbf[r][8 * half + 4]);
      *reinterpret_cast<int4*>(poseC + ((size_t)i * 64 + r) * 16 + 8 * half) = u.q;
    }
  }

  const f32x16 zero16 = {};

  if (PASS == 1) {
    // ---- phase A (swapped): score(r,c) = sum_l (V-mu)^2, in-register ----
#pragma unroll
    for (int rowhalf = 0; rowhalf < 2; ++rowhalf) {
      ABfrag A;
      {
        const int r = rowhalf * 32 + ln31;
        A.h[0] = *reinterpret_cast<const short4v*>(&pbf[r][8 * h]);
        A.h[1] = *reinterpret_cast<const short4v*>(&pbf[r][8 * h + 4]);
      }
      const int b = (rowhalf * 32 + ln31) >> 4;
#pragma unroll
      for (int cl_ = 0; cl_ < 2; ++cl_) {
        float sc = 0.f;
#pragma unroll
        for (int lh = 0; lh < 2; ++lh) {
          // D[m=l][n=r]: lane col = r, regs = l
          const f32x16 acc = __builtin_amdgcn_mfma_f32_32x32x16_bf16(
              wf[cl_ * 2 + lh], A.v, zero16, 0, 0, 0);
          const float* mrow = &mu_s[b * CC + cbase + cl_][lh * 32 + 4 * h];
#pragma unroll
          for (int g = 0; g < 4; ++g) {  // l = lh*32 + 4h + 8g + k
            const float4 m4 = *reinterpret_cast<const float4*>(mrow + 8 * g);
            float d;
            d = acc[4 * g + 0] - m4.x; sc = fmaf(d, d, sc);
            d = acc[4 * g + 1] - m4.y; sc = fmaf(d, d, sc);
            d = acc[4 * g + 2] - m4.z; sc = fmaf(d, d, sc);
            d = acc[4 * g + 3] - m4.w; sc = fmaf(d, d, sc);
          }
        }
        sc += __shfl_xor(sc, 32, 64);  // combine h halves (l+-4 groups)
        if (h == 0) sc_s[rowhalf * 32 + ln31][cbase + cl_] = sc;
      }
    }
    __syncthreads();
    // ---- softmax over c (all 512 threads, 8x redundant rows) ----
    {
      const int r = t & 63, cq = t >> 6, b = r >> 4;
      float s[16];
#pragma unroll
      for (int cc = 0; cc < 16; ++cc) s[cc] = T_s[b * CC + cc] - sc_s[r][cc];
      float m = s[0];
#pragma unroll
      for (int cc = 1; cc < 16; ++cc) m = fmaxf(m, s[cc]);
      float den = 0.f;
#pragma unroll
      for (int cc = 0; cc < 16; ++cc) { s[cc] = __expf(s[cc] - m); den += s[cc]; }
      const float a = act_s[r] / den;
#pragma unroll
      for (int k = 0; k < 2; ++k) {
        const int cc = 2 * cq + k;
        const float rh = fmaxf(s[cc] * a, 0.01f);
        rh2[cc][r] = rh;
        atomicAdd(&sr_s[b * CC + cc], rh);
      }
    }
    __syncthreads();
  }

  // ---- phase B: S1/S2 (original orientation; r-sum in-register) ----
#pragma unroll
  for (int pair = 0; pair < 2; ++pair) {
    ABfrag A;
    {
      const int r = pair * 32 + ln31;
      A.h[0] = *reinterpret_cast<const short4v*>(&pbf[r][8 * h]);
      A.h[1] = *reinterpret_cast<const short4v*>(&pbf[r][8 * h + 4]);
    }
    float p1[4][2] = {}, p2[4][2] = {};
#pragma unroll
    for (int cl_ = 0; cl_ < 2; ++cl_) {
      float rq[16];
      if (PASS == 1) {
#pragma unroll
        for (int g = 0; g < 4; ++g) {
          const float4 v = *reinterpret_cast<const float4*>(
              &rh2[cbase + cl_][pair * 32 + 8 * g + 4 * h]);
          rq[4 * g + 0] = v.x; rq[4 * g + 1] = v.y;
          rq[4 * g + 2] = v.z; rq[4 * g + 3] = v.w;
        }
      } else {
#pragma unroll
        for (int g = 0; g < 4; ++g) {
          const float4 v = *reinterpret_cast<const float4*>(
              &act_s[pair * 32 + 8 * g + 4 * h]);
          rq[4 * g + 0] = fmaxf(v.x * 0.0625f, 0.01f);
          rq[4 * g + 1] = fmaxf(v.y * 0.0625f, 0.01f);
          rq[4 * g + 2] = fmaxf(v.z * 0.0625f, 0.01f);
          rq[4 * g + 3] = fmaxf(v.w * 0.0625f, 0.01f);
        }
      }
#pragma unroll
      for (int lh = 0; lh < 2; ++lh) {
        const f32x16 acc = __builtin_amdgcn_mfma_f32_32x32x16_bf16(
            A.v, wf[cl_ * 2 + lh], zero16, 0, 0, 0);
        const int t4 = cl_ * 2 + lh;
#pragma unroll
        for (int j = 0; j < 16; ++j) {
          const float v = acc[j];
          const float rv = rq[j] * v;
          p1[t4][j >> 3] += rv;
          p2[t4][j >> 3] = fmaf(rv, v, p2[t4][j >> 3]);
        }
      }
    }
#pragma unroll
    for (int t4 = 0; t4 < 4; ++t4)
#pragma unroll
      for (int bh = 0; bh < 2; ++bh) {
        float v1 = p1[t4][bh]; v1 += __shfl_xor(v1, 32, 64);
        float v2 = p2[t4][bh]; v2 += __shfl_xor(v2, 32, 64);
        const int b = pair * 2 + bh, c = cbase + (t4 >> 1);
        const int idx = (b * CC + c) * LV + (t4 & 1) * 32 + ln31;
        if (STORE) {
          if (h == 0) { S1p[idx] = v1; S2p[idx] = v2; }
        } else if (h == 0) {
          atomicAdd(&S1p[idx], v1); atomicAdd(&S2p[idx], v2);
        }
      }
  }

  // ---- Sr ----
  if (PASS == 1) {
    if (t < 64) { if (STORE) Srp[t] = sr_s[t]; else atomicAdd(&Srp[t], sr_s[t]); }
  } else {
    if (t < 64) {
      const int b = t >> 4;
      float s = 0.f;
#pragma unroll
      for (int xy = 0; xy < 16; ++xy) s += fmaxf(act_s[b * 16 + xy] * 0.0625f, 0.01f);
      if (STORE) Srp[t] = s; else atomicAdd(&Srp[t], s);
    }
  }
}

// ---- two-stage tree reduce, plain stores (no memset, no atomics) ----
__global__ void reduce_stageA(const float* __restrict__ Spart,
                              float* __restrict__ Spart2) {
  const int idx = blockIdx.x * 256 + threadIdx.x;
  if (idx >= SLABTOT) return;
  const float* base = Spart + (size_t)(blockIdx.y * 32) * SLABTOT + idx;
  float a = 0.f;
#pragma unroll 8
  for (int s = 0; s < 32; ++s) a += base[(size_t)s * SLABTOT];
  Spart2[(size_t)blockIdx.y * SLABTOT + idx] = a;
}

__global__ void reduce_stageB(const float* __restrict__ Spart2,
                              float* __restrict__ Sred) {
  const int idx = blockIdx.x * 256 + threadIdx.x;
  if (idx >= SLABTOT) return;
  float a = 0.f;
#pragma unroll 8
  for (int s = 0; s < 32; ++s) a += Spart2[(size_t)s * SLABTOT + idx];
  Sred[idx] = a;
}

// legacy atomic reduce (small-ws fallback only)
__global__ void reduce_slabs(const float* __restrict__ Spart, float* __restrict__ Sred,
                             int nslab, int chunk) {
  const int idx = blockIdx.x * 256 + threadIdx.x;
  if (idx >= SLABTOT) return;
  const int s0 = blockIdx.y * chunk;
  const int s1 = min(s0 + chunk, nslab);
  float a = 0.f;
#pragma unroll 8
  for (int s = s0; s < s1; s++) a += Spart[(size_t)s * SLABTOT + idx];
  atomicAdd(&Sred[idx], a);
}

// 512 threads: (bc = t>>3, part = t&7) handles 8 l's; LDS-reduce lsum.
// (This exact decomposition ran correct in the round-8 fused kernel.)
template <int FINAL>
__global__ void stats_post(const float* __restrict__ Sred,
                           const float* __restrict__ beta_v,
                           const float* __restrict__ beta_a,
                           const float* __restrict__ lam,
                           float* __restrict__ mu_out, float* __restrict__ T_out,
                           float* __restrict__ out) {
  __shared__ float lsum_s[64][8];
  const int t = threadIdx.x;
  const int bc = t >> 3, part = t & 7;
  const float inv = 1.f / Sred[2 * SLAB + bc];
  float lsl = 0.f;
#pragma unroll
  for (int q = 0; q < 8; ++q) {
    const int l = part * 8 + q;
    const int idx = bc * 64 + l;
    const float m = Sred[idx] * inv;
    const float s2 = fmaxf(Sred[SLAB + idx] * inv - m * m, 0.01f);
    lsl += logf(s2);
    if (FINAL) out[(size_t)(bc >> 4) * 1040 + (bc & 15) * 64 + l] = m;
    else mu_out[idx] = m;
  }
  lsum_s[bc][part] = lsl;
  __syncthreads();
  if (t < 64) {
    float lsum = 0.f;
#pragma unroll
    for (int q = 0; q < 8; ++q) lsum += lsum_s[t][q];
    const float sr = Sred[2 * SLAB + t];
    const float z = lam[0] * (beta_a[t & 15] - (64.f * beta_v[0] + lsum) * sr);
    const float ac = 1.f / (1.f + expf(-z));
    if (FINAL) out[(size_t)(t >> 4) * 1040 + 1024 + (t & 15)] = ac;
    else T_out[t] = logf(ac) - 0.5f * (64.f * LOG_2PI_F + lsum);
  }
}

extern "C" void kernel_launch(void* const* d_in, const int* in_sizes, int n_in,
                              void* d_out, int out_size, void* d_ws, size_t ws_size,
                              hipStream_t stream) {
  const float* x = (const float*)d_in[0];
  const float* W = (const float*)d_in[1];
  const float* beta_v = (const float*)d_in[2];
  const float* beta_a = (const float*)d_in[3];
  const float* lam = (const float*)d_in[4];
  float* out = (float*)d_out;

  const size_t base_floats = (size_t)BC * SLABTOT + SLABTOT + SLAB + 64;
  const size_t need_store = base_floats * sizeof(float);
  const size_t need_cache = need_store + WBF_ELEMS * 2 + POSE_ELEMS * 2 +
                            ACT_ELEMS * sizeof(float) +
                            (size_t)32 * SLABTOT * sizeof(float);

  const bool cache = (ws_size >= need_cache);
  const int nslab = (ws_size >= need_store) ? BC : NSLAB_SM;
  const bool store = (nslab == BC);

  float* Spart = (float*)d_ws;
  float* Sred = Spart + (size_t)nslab * SLABTOT;
  float* muW = Sred + SLABTOT;
  float* Tw = muW + SLAB;
  unsigned short* WbfC = (unsigned short*)(Tw + 64);
  unsigned short* poseC = WbfC + WBF_ELEMS;
  float* actC = (float*)(poseC + POSE_ELEMS);
  float* Spart2 = actC + ACT_ELEMS;

  const dim3 agrid((SLABTOT + 255) / 256, 32);
  const dim3 bgrid((SLABTOT + 255) / 256);

  if (cache) {
    // ---- pass 0 ----
    em_sweep<0, 1, 1><<<dim3(BC), dim3(512), 0, stream>>>(x, W, nullptr, nullptr, Spart, nslab, WbfC, poseC, actC);
    reduce_stageA<<<agrid, dim3(256), 0, stream>>>(Spart, Spart2);
    reduce_stageB<<<bgrid, dim3(256), 0, stream>>>(Spart2, Sred);
    stats_post<0><<<dim3(1), dim3(512), 0, stream>>>(Sred, beta_v, beta_a, lam, muW, Tw, nullptr);
    // ---- pass 1 ----
    em_sweep<1, 1, 1><<<dim3(BC), dim3(512), 0, stream>>>(x, W, muW, Tw, Spart, nslab, WbfC, poseC, actC);
    reduce_stageA<<<agrid, dim3(256), 0, stream>>>(Spart, Spart2);
    reduce_stageB<<<bgrid, dim3(256), 0, stream>>>(Spart2, Sred);
    stats_post<1><<<dim3(1), dim3(512), 0, stream>>>(Sred, beta_v, beta_a, lam, nullptr, nullptr, out);
    return;
  }

  // ---- fallback: legacy memset + atomic reduce ----
  const int chunk = 32;
  const dim3 rgrid((SLABTOT + 255) / 256, (nslab + chunk - 1) / chunk);

  if (!store) hipMemsetAsync(Spart, 0, (size_t)nslab * SLABTOT * sizeof(float), stream);
  hipMemsetAsync(Sred, 0, SLABTOT * sizeof(float), stream);
  if (store) em_sweep<0, 1, 0><<<dim3(BC), dim3(512), 0, stream>>>(x, W, nullptr, nullptr, Spart, nslab, nullptr, nullptr, nullptr);
  else       em_sweep<0, 0, 0><<<dim3(BC), dim3(512), 0, stream>>>(x, W, nullptr, nullptr, Spart, nslab, nullptr, nullptr, nullptr);
  reduce_slabs<<<rgrid, dim3(256), 0, stream>>>(Spart, Sred, nslab, chunk);
  stats_post<0><<<dim3(1), dim3(512), 0, stream>>>(Sred, beta_v, beta_a, lam, muW, Tw, nullptr);

  if (!store) hipMemsetAsync(Spart, 0, (size_t)nslab * SLABTOT * sizeof(float), stream);
  hipMemsetAsync(Sred, 0, SLABTOT * sizeof(float), stream);
  if (store) em_sweep<1, 1, 0><<<dim3(BC), dim3(512), 0, stream>>>(x, W, muW, Tw, Spart, nslab, nullptr, nullptr, nullptr);
  else       em_sweep<1, 0, 0><<<dim3(BC), dim3(512), 0, stream>>>(x, W, muW, Tw, Spart, nslab, nullptr, nullptr, nullptr);
  reduce_slabs<<<rgrid, dim3(256), 0, stream>>>(Spart, Sred, nslab, chunk);
  stats_post<1><<<dim3(1), dim3(512), 0, stream>>>(Sred, beta_v, beta_a, lam, nullptr, nullptr, out);
}